// Round 1
// baseline (575.647 us; speedup 1.0000x reference)
//
#include <hip/hip_runtime.h>
#include <stdint.h>

#define B_ 4
#define T_ 500
#define L_ 120000
#define NH_ 100
// RWR(16) level sizes (verified R9 — DO NOT TOUCH)
#define N1_ 7500
#define N2_ 469
#define N2P_ 7504
#define N3_ 30
#define N3P_ 480
#define N4_ 2
#define N4P_ 32

#define ACT_NONE 0
#define ACT_LRELU 1
#define ACT_SOFTPLUS 2
#define ACT_SIGMOID 3

#define CCT 128  // cc chunk for conv tiling
#define DWC 64   // cc chunk for fused dw+pw (keeps LDS = 33 KB)

// ---------------- Threefry2x32-20 (verified R9) ----------------
__host__ __device__ __forceinline__ uint32_t tf_rotl(uint32_t v, int d) {
  return (v << d) | (v >> (32 - d));
}
__host__ __device__ __forceinline__ void tf_block(uint32_t k0, uint32_t k1,
                                                  uint32_t& x0, uint32_t& x1) {
  uint32_t k2 = k0 ^ k1 ^ 0x1BD11BDAu;
  x0 += k0; x1 += k1;
#define TF_R(d) x0 += x1; x1 = tf_rotl(x1, (d)); x1 ^= x0;
  TF_R(13) TF_R(15) TF_R(26) TF_R(6)   x0 += k1; x1 += k2 + 1u;
  TF_R(17) TF_R(29) TF_R(16) TF_R(24)  x0 += k2; x1 += k0 + 2u;
  TF_R(13) TF_R(15) TF_R(26) TF_R(6)   x0 += k0; x1 += k1 + 3u;
  TF_R(17) TF_R(29) TF_R(16) TF_R(24)  x0 += k1; x1 += k2 + 4u;
  TF_R(13) TF_R(15) TF_R(26) TF_R(6)   x0 += k2; x1 += k0 + 5u;
#undef TF_R
}

__device__ __forceinline__ float erfinv_xla(float x) {
  float w = -log1pf(-(x * x));
  float p;
  if (w < 5.0f) {
    w = w - 2.5f;
    p = 2.81022636e-08f;
    p = fmaf(p, w, 3.43273939e-07f);
    p = fmaf(p, w, -3.5233877e-06f);
    p = fmaf(p, w, -4.39150654e-06f);
    p = fmaf(p, w, 0.00021858087f);
    p = fmaf(p, w, -0.00125372503f);
    p = fmaf(p, w, -0.00417768164f);
    p = fmaf(p, w, 0.246640727f);
    p = fmaf(p, w, 1.50140941f);
  } else {
    w = sqrtf(w) - 3.0f;
    p = -0.000200214257f;
    p = fmaf(p, w, 0.000100950558f);
    p = fmaf(p, w, 0.00134934322f);
    p = fmaf(p, w, -0.00367342844f);
    p = fmaf(p, w, 0.00573950773f);
    p = fmaf(p, w, -0.0076224613f);
    p = fmaf(p, w, 0.00943887047f);
    p = fmaf(p, w, 1.00167406f);
    p = fmaf(p, w, 2.83297682f);
  }
  return p * x;
}

__device__ __forceinline__ float jax_normal(uint32_t k0, uint32_t k1, uint32_t e) {
  uint32_t x0 = 0u, x1 = e;
  tf_block(k0, k1, x0, x1);
  uint32_t bits = x0 ^ x1;
  float u = __uint_as_float((bits >> 9) | 0x3f800000u) - 1.0f;
  float v = __fadd_rn(__fmul_rn(u, 2.0f), -0x1.fffffep-1f);
  v = fmaxf(v, -0x1.fffffep-1f);
  return __fmul_rn((float)1.4142135623730951, erfinv_xla(v));
}

// accurate sin of an EXACT f32 argument: f64 Cody-Waite reduction (verified R9)
__device__ __forceinline__ float sin_acc(float xf) {
  double x = (double)xf;
  double kd = rint(x * 6.3661977236758138e-01);
  double r = fma(-kd, 1.5707963267948966e+00, x);
  r = fma(-kd, 6.1232339957367660e-17, r);
  float rf = (float)r;
  float y = rf * rf;
  float ps = fmaf(y, 2.7557319e-06f, -1.9841270e-04f);
  ps = fmaf(y, ps, 8.3333335e-03f);
  ps = fmaf(y, ps, -0.16666667f);
  float s = fmaf(rf * y, ps, rf);
  float pc = fmaf(y, -2.7557319e-07f, 2.4801587e-05f);
  pc = fmaf(y, pc, -1.3888889e-03f);
  pc = fmaf(y, pc, 4.1666668e-02f);
  pc = fmaf(y, pc, -0.5f);
  float c = fmaf(y, pc, 1.0f);
  int q = ((int)kd) & 3;
  float rs = (q & 1) ? c : s;
  return (q & 2) ? -rs : rs;
}

__device__ __forceinline__ float apply_act(float v, int act) {
  switch (act) {
    case ACT_LRELU:    return v >= 0.0f ? v : 0.1f * v;
    case ACT_SOFTPLUS: return fmaxf(v, 0.0f) + log1pf(expf(-fabsf(v)));
    case ACT_SIGMOID:  return 1.0f / (1.0f + expf(-v));
  }
  return v;
}

// ---------------- conv kernels ----------------
// Tiled K=3 conv: block = 64 t-lanes x 4 o-groups, thread computes 4 outputs.
// FMA chain order per output matches reference exactly -> bitwise identical.
__global__ void __launch_bounds__(256) conv3_tiled(
    const float* __restrict__ x, const float* __restrict__ w,
    const float* __restrict__ bias, float* __restrict__ y,
    int Cin, int Cout, int act) {
  __shared__ float sx[CCT][66];
  int t0 = blockIdx.x * 64;
  int o0 = blockIdx.y * 16;
  int b = blockIdx.z;
  int lane = threadIdx.x & 63;
  int og = threadIdx.x >> 6;
  int t = t0 + lane;
  int o[4];
  float acc[4];
#pragma unroll
  for (int i = 0; i < 4; ++i) {
    o[i] = o0 + og + 4 * i;
    acc[i] = (o[i] < Cout) ? bias[o[i]] : 0.0f;
  }
  for (int c0 = 0; c0 < Cin; c0 += CCT) {
    __syncthreads();
    for (int idx = threadIdx.x; idx < CCT * 66; idx += 256) {
      int cc = idx / 66, j = idx - cc * 66;
      int tt = t0 - 1 + j;
      sx[cc][j] = (tt >= 0 && tt < T_) ? x[((size_t)b * Cin + c0 + cc) * T_ + tt] : 0.0f;
    }
    __syncthreads();
    for (int cc = 0; cc < CCT; ++cc) {
      float xm = sx[cc][lane];
      float x0v = sx[cc][lane + 1];
      float xp = sx[cc][lane + 2];
#pragma unroll
      for (int i = 0; i < 4; ++i) {
        const float* wo = w + ((size_t)o[i] * Cin + c0 + cc) * 3;
        acc[i] = fmaf(xm, wo[0], acc[i]);
        acc[i] = fmaf(x0v, wo[1], acc[i]);
        acc[i] = fmaf(xp, wo[2], acc[i]);
      }
    }
  }
  if (t < T_) {
#pragma unroll
    for (int i = 0; i < 4; ++i)
      if (o[i] < Cout) y[((size_t)b * Cout + o[i]) * T_ + t] = apply_act(acc[i], act);
  }
}

// Fused depthwise-K3 (groups=Cin) -> pointwise Cin->Cout.
// dw result staged in LDS (never touches HBM). dw FMA chain identical to the old
// dw_conv3; pw accumulation ascends cc globally with acc seeded from bias ->
// bitwise identical to dw_conv3 followed by pw_tiled.
__global__ void __launch_bounds__(256) dwpw_tiled(
    const float* __restrict__ x, const float* __restrict__ wd,
    const float* __restrict__ bd, const float* __restrict__ wp,
    const float* __restrict__ bp, float* __restrict__ y,
    int Cin, int Cout, int act) {
  __shared__ float sx[DWC][66];
  __shared__ float sd[DWC][64];
  int t0 = blockIdx.x * 64;
  int o0 = blockIdx.y * 16;
  int b = blockIdx.z;
  int lane = threadIdx.x & 63;
  int og = threadIdx.x >> 6;
  int t = t0 + lane;
  int o[4];
  float acc[4];
#pragma unroll
  for (int i = 0; i < 4; ++i) {
    o[i] = o0 + og + 4 * i;
    acc[i] = (o[i] < Cout) ? bp[o[i]] : 0.0f;
  }
  for (int c0 = 0; c0 < Cin; c0 += DWC) {
    __syncthreads();
    for (int idx = threadIdx.x; idx < DWC * 66; idx += 256) {
      int cc = idx / 66, j = idx - cc * 66;
      int tt = t0 - 1 + j;
      sx[cc][j] = (tt >= 0 && tt < T_) ? x[((size_t)b * Cin + c0 + cc) * T_ + tt] : 0.0f;
    }
    __syncthreads();
    // depthwise: output j corresponds to t = t0 + j; xm=sx[cc][j], x0=sx[cc][j+1], xp=sx[cc][j+2]
    for (int idx = threadIdx.x; idx < DWC * 64; idx += 256) {
      int cc = idx >> 6, j = idx & 63;
      const float* wc = wd + (size_t)(c0 + cc) * 3;
      sd[cc][j] = fmaf(sx[cc][j], wc[0],
                  fmaf(sx[cc][j + 1], wc[1],
                  fmaf(sx[cc][j + 2], wc[2], bd[c0 + cc])));
    }
    __syncthreads();
    for (int cc = 0; cc < DWC; ++cc) {
      float xv = sd[cc][lane];
#pragma unroll
      for (int i = 0; i < 4; ++i)
        acc[i] = fmaf(xv, wp[(size_t)o[i] * Cin + c0 + cc], acc[i]);
    }
  }
  if (t < T_) {
#pragma unroll
    for (int i = 0; i < 4; ++i)
      if (o[i] < Cout) y[((size_t)b * Cout + o[i]) * T_ + t] = apply_act(acc[i], act);
  }
}

// Tiled K=1 pointwise conv. cc ascending, acc=bias start -> bitwise identical.
__global__ void __launch_bounds__(256) pw_tiled(
    const float* __restrict__ x, const float* __restrict__ w,
    const float* __restrict__ bias, float* __restrict__ y,
    int Cin, int Cout, int act) {
  __shared__ float sx[CCT][64];
  int t0 = blockIdx.x * 64;
  int o0 = blockIdx.y * 16;
  int b = blockIdx.z;
  int lane = threadIdx.x & 63;
  int og = threadIdx.x >> 6;
  int t = t0 + lane;
  int o[4];
  float acc[4];
#pragma unroll
  for (int i = 0; i < 4; ++i) {
    o[i] = o0 + og + 4 * i;
    acc[i] = (o[i] < Cout) ? bias[o[i]] : 0.0f;
  }
  for (int c0 = 0; c0 < Cin; c0 += CCT) {
    __syncthreads();
    for (int idx = threadIdx.x; idx < CCT * 64; idx += 256) {
      int cc = idx >> 6, j = idx & 63;
      int tt = t0 + j;
      sx[cc][j] = (tt < T_) ? x[((size_t)b * Cin + c0 + cc) * T_ + tt] : 0.0f;
    }
    __syncthreads();
    for (int cc = 0; cc < CCT; ++cc) {
      float xv = sx[cc][lane];
#pragma unroll
      for (int i = 0; i < 4; ++i)
        acc[i] = fmaf(xv, w[(size_t)o[i] * Cin + c0 + cc], acc[i]);
    }
  }
  if (t < T_) {
#pragma unroll
    for (int i = 0; i < 4; ++i)
      if (o[i] < Cout) y[((size_t)b * Cout + o[i]) * T_ + t] = apply_act(acc[i], act);
  }
}

__global__ void pw_small(const float* __restrict__ x, const float* __restrict__ w,
                         const float* __restrict__ bias, float* __restrict__ y,
                         int Cin, int Cout, int act) {
  int idx = blockIdx.x * blockDim.x + threadIdx.x;
  int total = B_ * Cout * T_;
  if (idx >= total) return;
  int t = idx % T_;
  int o = (idx / T_) % Cout;
  int b = idx / (T_ * Cout);
  float acc = bias[o];
  const float* wo = w + (size_t)o * Cin;
  const float* xb = x + (size_t)b * Cin * T_ + t;
  for (int cc = 0; cc < Cin; ++cc) acc = fmaf(wo[cc], xb[(size_t)cc * T_], acc);
  y[((size_t)b * Cout + o) * T_ + t] = apply_act(acc, act);
}

__global__ void shaped_kernel(const float* __restrict__ ha, const float* __restrict__ fp,
                              const float* __restrict__ f0, float* __restrict__ out) {
  int t = blockIdx.x, b = blockIdx.y, h = threadIdx.x;
  __shared__ float ff[5], nm[5];
  if (h < 10) {
    float v = fp[((size_t)b * 10 + h) * T_ + t];
    if (h < 5) {
      ff[h] = 200.0f + 3300.0f * (1.0f / (1.0f + expf(-v)));
    } else {
      float bw = 50.0f + 150.0f * (fmaxf(v, 0.0f) + log1pf(expf(-fabsf(v))));
      nm[h - 5] = bw * bw;
    }
  }
  __syncthreads();
  if (h >= NH_) return;
  float hfreq = (float)(h + 1) * f0[(size_t)b * T_ + t];
  float g = 1.0f;
  for (int i = 0; i < 5; ++i) {
    float d = hfreq - ff[i];
    float den = d * d + nm[i];
    float res = nm[i] / fmaxf(den, 1e-5f);
    g = g * (0.8f + 0.2f * res);
  }
  out[((size_t)b * NH_ + h) * T_ + t] = ha[((size_t)b * NH_ + h) * T_ + t] * g;
}

// ---- fused terms + RWR level-1: computes per-element term inline (identical
// f32 ops to the old terms_kernel), then the 16-wide inclusive prefix sum ----
__global__ void terms_l1(const float* __restrict__ f0, float* __restrict__ A1) {
  int gid = blockIdx.x * blockDim.x + threadIdx.x;
  if (gid >= B_ * N1_) return;
  int b = gid / N1_, w = gid - b * N1_;
  const float* f0b = f0 + (size_t)b * T_;
  float* a = A1 + (size_t)b * L_ + (size_t)w * 16;
  const float RINV = (float)(500.0 / 120000.0);
  float S = 0.0f;
  int lbase = w * 16;
  for (int i = 0; i < 16; ++i) {
    int l = lbase + i;
    float pos = __fsub_rn(__fmul_rn(__fadd_rn((float)l, 0.5f), RINV), 0.5f);
    pos = fminf(fmaxf(pos, 0.0f), 499.0f);
    int lo = (int)floorf(pos);
    int hi = lo + 1; hi = hi < (T_ - 1) ? hi : (T_ - 1);
    float wt = __fsub_rn(pos, (float)lo);
    float omw = __fsub_rn(1.0f, wt);
    float f0up = __fadd_rn(__fmul_rn(f0b[lo], omw), __fmul_rn(f0b[hi], wt));
    float trm = __fdiv_rn(__fmul_rn((float)6.283185307179586, f0up), 24000.0f);
    S = __fadd_rn(S, trm);
    a[i] = S;
  }
}

// ---- fused RWR mid-chain: l2,l3,l4,l5,e3,e2 in ONE single-block kernel.
// __syncthreads() between phases gives block-wide global-memory visibility.
// Per-item arithmetic identical to the old rwr_l2..rwr_e2 kernels. ----
__global__ void __launch_bounds__(256) rwr_mid(
    const float* __restrict__ A1, float* __restrict__ A2, float* __restrict__ A3,
    float* __restrict__ A4, float* __restrict__ E5, float* __restrict__ E3o,
    float* __restrict__ E2o) {
  int tid = threadIdx.x;
  // l2
  for (int gid = tid; gid < B_ * N2_; gid += 256) {
    int b = gid / N2_, w = gid - b * N2_;
    float S = 0.0f;
    for (int m = 0; m < 16; ++m) {
      int i = w * 16 + m;
      float v = (i < N1_) ? A1[(size_t)b * L_ + (size_t)i * 16 + 15] : 0.0f;
      S = __fadd_rn(S, v);
      A2[(size_t)b * N2P_ + i] = S;
    }
  }
  __syncthreads();
  // l3
  for (int gid = tid; gid < B_ * N3_; gid += 256) {
    int b = gid / N3_, w = gid - b * N3_;
    float S = 0.0f;
    for (int m = 0; m < 16; ++m) {
      int i = w * 16 + m;
      float v = (i < N2_) ? A2[(size_t)b * N2P_ + (size_t)i * 16 + 15] : 0.0f;
      S = __fadd_rn(S, v);
      A3[(size_t)b * N3P_ + i] = S;
    }
  }
  __syncthreads();
  // l4
  for (int gid = tid; gid < B_ * N4_; gid += 256) {
    int b = gid / N4_, w = gid - b * N4_;
    float S = 0.0f;
    for (int m = 0; m < 16; ++m) {
      int i = w * 16 + m;
      float v = (i < N3_) ? A3[(size_t)b * N3P_ + (size_t)i * 16 + 15] : 0.0f;
      S = __fadd_rn(S, v);
      A4[(size_t)b * N4P_ + i] = S;
    }
  }
  __syncthreads();
  // l5
  if (tid < B_) {
    E5[tid * N4_ + 0] = 0.0f;
    E5[tid * N4_ + 1] = A4[(size_t)tid * N4P_ + 15];
  }
  __syncthreads();
  // e3
  for (int gid = tid; gid < B_ * N3_; gid += 256) {
    int b = gid / N3_, k = gid - b * N3_;
    float v = 0.0f;
    if (k > 0) {
      int i = k - 1;
      v = __fadd_rn(E5[b * N4_ + (i >> 4)], A4[(size_t)b * N4P_ + i]);
    }
    E3o[b * N3_ + k] = v;
  }
  __syncthreads();
  // e2
  for (int gid = tid; gid < B_ * N2_; gid += 256) {
    int b = gid / N2_, j = gid - b * N2_;
    float v = 0.0f;
    if (j > 0) {
      int i = j - 1;
      v = __fadd_rn(E3o[b * N3_ + (i >> 4)], A3[(size_t)b * N3P_ + i]);
    }
    E2o[b * N2_ + j] = v;
  }
}

// ---------------- main synthesis kernel (numerics unchanged; rwr_e1 inlined:
// E1o[b][r] == (r>0 ? __fadd_rn(E2o[b][(r-1)>>4], A2[b][r-1]) : 0)) ----------
__global__ void __launch_bounds__(256) main_kernel(
    const float* __restrict__ A1, const float* __restrict__ A2,
    const float* __restrict__ E2o,
    const float* __restrict__ shaped, const float* __restrict__ q,
    const float* __restrict__ f0, float* __restrict__ out,
    uint32_t k10, uint32_t k11, uint32_t k20, uint32_t k21, uint32_t k30, uint32_t k31) {
  const float RINV = (float)(500.0 / 120000.0);
  int b = blockIdx.y;
  int l0 = blockIdx.x * 256;
  int l = l0 + threadIdx.x;
  __shared__ float ls[4][NH_];
  float p0 = __fsub_rn(__fmul_rn(__fadd_rn((float)l0, 0.5f), RINV), 0.5f);
  p0 = fminf(fmaxf(p0, 0.0f), 499.0f);
  int lo0 = (int)floorf(p0);
  for (int i = threadIdx.x; i < 4 * NH_; i += 256) {
    int j = i / NH_, h = i - j * NH_;
    int col = lo0 + j; col = col < (T_ - 1) ? col : (T_ - 1);
    ls[j][h] = shaped[((size_t)b * NH_ + h) * T_ + col];
  }
  __syncthreads();
  if (l >= L_) return;

  float pos = __fsub_rn(__fmul_rn(__fadd_rn((float)l, 0.5f), RINV), 0.5f);
  pos = fminf(fmaxf(pos, 0.0f), 499.0f);
  int lo = (int)floorf(pos);
  int hi = lo + 1; hi = hi < (T_ - 1) ? hi : (T_ - 1);
  float w = __fsub_rn(pos, (float)lo);
  float omw = __fsub_rn(1.0f, w);

  const float* f0b = f0 + (size_t)b * T_;
  float f0up = __fadd_rn(__fmul_rn(f0b[lo], omw), __fmul_rn(f0b[hi], w));
  const float* qb = q + (size_t)b * 3 * T_;
  float q0 = __fadd_rn(__fmul_rn(qb[lo], omw), __fmul_rn(qb[hi], w));
  float q1 = __fadd_rn(__fmul_rn(qb[T_ + lo], omw), __fmul_rn(qb[T_ + hi], w));
  float q2 = __fadd_rn(__fmul_rn(qb[2 * T_ + lo], omw), __fmul_rn(qb[2 * T_ + hi], w));
  float jit = __fmul_rn(q0, 0.05f);
  float shm = __fmul_rn(q1, 0.15f);
  float brt = __fmul_rn(q2, 0.3f);

  uint32_t e = (uint32_t)(b * L_ + l);
  float n1 = jax_normal(k10, k11, e);
  float n2 = jax_normal(k20, k21, e);
  float n3 = jax_normal(k30, k31, e);

  // inlined rwr_e1
  float e1v = 0.0f;
  int r = l >> 4;
  if (r > 0) {
    int i = r - 1;
    e1v = __fadd_rn(E2o[b * N2_ + (i >> 4)], A2[(size_t)b * N2P_ + i]);
  }
  float phf = __fadd_rn(e1v, A1[(size_t)b * L_ + l]);
  float jph = __fadd_rn(phf, __fmul_rn(jit, n1));

  int jlo = lo - lo0;
  int jhi = hi - lo0; jhi = jhi < 3 ? jhi : 3;

  float acc = 0.0f;
  for (int h = 1; h <= NH_; ++h) {
    float amp = __fadd_rn(__fmul_rn(ls[jlo][h - 1], omw), __fmul_rn(ls[jhi][h - 1], w));
    float hf = (float)h;
    float arg = __fmul_rn(jph, hf);
    float s = sin_acc(arg);
    float m = (__fmul_rn(hf, f0up) < 12000.0f) ? 1.0f : 0.0f;
    acc = __fadd_rn(acc, __fmul_rn(__fmul_rn(amp, s), m));
  }
  float env = __fadd_rn(1.0f, __fmul_rn(n2, shm));
  out[(size_t)b * L_ + l] = __fadd_rn(__fmul_rn(acc, env), __fmul_rn(n3, brt));
}

extern "C" void kernel_launch(void* const* d_in, const int* in_sizes, int n_in,
                              void* d_out, int out_size, void* d_ws, size_t ws_size,
                              hipStream_t stream) {
  const float* f0    = (const float*)d_in[0];
  const float* cond  = (const float*)d_in[1];
  const float* ha_w1 = (const float*)d_in[2];
  const float* ha_b1 = (const float*)d_in[3];
  const float* ha_w2 = (const float*)d_in[4];
  const float* ha_b2 = (const float*)d_in[5];
  const float* ha_w3 = (const float*)d_in[6];
  const float* ha_b3 = (const float*)d_in[7];
  const float* ha_w4 = (const float*)d_in[8];
  const float* ha_b4 = (const float*)d_in[9];
  const float* ha_w5 = (const float*)d_in[10];
  const float* ha_b5 = (const float*)d_in[11];
  const float* fm_w1 = (const float*)d_in[12];
  const float* fm_b1 = (const float*)d_in[13];
  const float* fm_w2 = (const float*)d_in[14];
  const float* fm_b2 = (const float*)d_in[15];
  const float* fm_w3 = (const float*)d_in[16];
  const float* fm_b3 = (const float*)d_in[17];
  const float* vq_w1 = (const float*)d_in[18];
  const float* vq_b1 = (const float*)d_in[19];
  const float* vq_w2 = (const float*)d_in[20];
  const float* vq_b2 = (const float*)d_in[21];
  const float* vq_w3 = (const float*)d_in[22];
  const float* vq_b3 = (const float*)d_in[23];
  float* out = (float*)d_out;

  // split(key(42), 3), foldlike/partitionable (verified)
  uint32_t kw[3][2];
  for (uint32_t j = 0; j < 3; ++j) {
    uint32_t x0 = 0u, x1 = j;
    tf_block(0u, 42u, x0, x1);
    kw[j][0] = x0; kw[j][1] = x1;
  }

  // workspace layout (floats)
  float* ws = (float*)d_ws;
  size_t off = 0;
  auto take = [&](size_t n) { float* p = ws + off; off += (n + 3) & ~(size_t)3; return p; };
  float* Abuf = take(512000);
  float* Bb   = take(512000);
  float* C    = take(512000);
  float* ha   = take((size_t)B_ * NH_ * T_);
  float* fp   = take((size_t)B_ * 10 * T_);
  float* qv   = take((size_t)B_ * 3 * T_);
  float* sh   = take((size_t)B_ * NH_ * T_);
  float* A1   = take((size_t)B_ * L_);
  float* A2   = take((size_t)B_ * N2P_);
  float* A3   = take((size_t)B_ * N3P_);
  float* A4   = take((size_t)B_ * N4P_);
  float* E5   = take((size_t)B_ * N4_);
  float* E3o  = take((size_t)B_ * N3_);
  float* E2o  = take((size_t)B_ * N2_);

  // phase chain: 2 launches (was 9)
  terms_l1<<<(B_ * N1_ + 255) / 256, 256, 0, stream>>>(f0, A1);
  rwr_mid<<<1, 256, 0, stream>>>(A1, A2, A3, A4, E5, E3o, E2o);

  // harmonic_amplitude_net: 3 launches (was 5)
  dwpw_tiled<<<dim3(8, 16, B_), 256, 0, stream>>>(cond, ha_w1, ha_b1, ha_w2, ha_b2, Bb, 128, 256, ACT_LRELU);
  dwpw_tiled<<<dim3(8, 16, B_), 256, 0, stream>>>(Bb, ha_w3, ha_b3, ha_w4, ha_b4, C, 256, 256, ACT_LRELU);
  pw_tiled<<<dim3(8, 7, B_), 256, 0, stream>>>(C, ha_w5, ha_b5, ha, 256, 100, ACT_SOFTPLUS);
  // formant net
  conv3_tiled<<<dim3(8, 16, B_), 256, 0, stream>>>(cond, fm_w1, fm_b1, Abuf, 128, 256, ACT_LRELU);
  conv3_tiled<<<dim3(8, 16, B_), 256, 0, stream>>>(Abuf, fm_w2, fm_b2, C, 256, 256, ACT_LRELU);
  pw_small<<<(B_ * 10 * T_ + 255) / 256, 256, 0, stream>>>(C, fm_w3, fm_b3, fp, 256, 10, ACT_NONE);
  // voice-quality net
  conv3_tiled<<<dim3(8, 8, B_), 256, 0, stream>>>(cond, vq_w1, vq_b1, Bb, 128, 128, ACT_LRELU);
  conv3_tiled<<<dim3(8, 4, B_), 256, 0, stream>>>(Bb, vq_w2, vq_b2, Abuf, 128, 64, ACT_LRELU);
  pw_small<<<(B_ * 3 * T_ + 255) / 256, 256, 0, stream>>>(Abuf, vq_w3, vq_b3, qv, 64, 3, ACT_SIGMOID);
  // shaped amplitudes
  shaped_kernel<<<dim3(T_, B_), 128, 0, stream>>>(ha, fp, f0, sh);
  // synthesis (rwr_e1 inlined)
  main_kernel<<<dim3((L_ + 255) / 256, B_), 256, 0, stream>>>(
      A1, A2, E2o, sh, qv, f0, out,
      kw[0][0], kw[0][1], kw[1][0], kw[1][1], kw[2][0], kw[2][1]);
  (void)in_sizes; (void)n_in; (void)out_size; (void)ws_size;
}

// Round 2
// 525.392 us; speedup vs baseline: 1.0957x; 1.0957x over previous
//
#include <hip/hip_runtime.h>
#include <stdint.h>

#define B_ 4
#define T_ 500
#define L_ 120000
#define NH_ 100
// RWR(16) level sizes (verified R9 — DO NOT TOUCH)
#define N1_ 7500
#define N2_ 469
#define N2P_ 7504
#define N3_ 30
#define N3P_ 480
#define N4_ 2
#define N4P_ 32

#define ACT_NONE 0
#define ACT_LRELU 1
#define ACT_SOFTPLUS 2
#define ACT_SIGMOID 3

#define K3C 64   // cc chunk for conv3 tiling
#define PWC 64   // cc chunk for pointwise tiling
#define DWC 64   // cc chunk for fused dw+pw

// ---------------- Threefry2x32-20 (verified R9) ----------------
__host__ __device__ __forceinline__ uint32_t tf_rotl(uint32_t v, int d) {
  return (v << d) | (v >> (32 - d));
}
__host__ __device__ __forceinline__ void tf_block(uint32_t k0, uint32_t k1,
                                                  uint32_t& x0, uint32_t& x1) {
  uint32_t k2 = k0 ^ k1 ^ 0x1BD11BDAu;
  x0 += k0; x1 += k1;
#define TF_R(d) x0 += x1; x1 = tf_rotl(x1, (d)); x1 ^= x0;
  TF_R(13) TF_R(15) TF_R(26) TF_R(6)   x0 += k1; x1 += k2 + 1u;
  TF_R(17) TF_R(29) TF_R(16) TF_R(24)  x0 += k2; x1 += k0 + 2u;
  TF_R(13) TF_R(15) TF_R(26) TF_R(6)   x0 += k0; x1 += k1 + 3u;
  TF_R(17) TF_R(29) TF_R(16) TF_R(24)  x0 += k1; x1 += k2 + 4u;
  TF_R(13) TF_R(15) TF_R(26) TF_R(6)   x0 += k2; x1 += k0 + 5u;
#undef TF_R
}

__device__ __forceinline__ float erfinv_xla(float x) {
  float w = -log1pf(-(x * x));
  float p;
  if (w < 5.0f) {
    w = w - 2.5f;
    p = 2.81022636e-08f;
    p = fmaf(p, w, 3.43273939e-07f);
    p = fmaf(p, w, -3.5233877e-06f);
    p = fmaf(p, w, -4.39150654e-06f);
    p = fmaf(p, w, 0.00021858087f);
    p = fmaf(p, w, -0.00125372503f);
    p = fmaf(p, w, -0.00417768164f);
    p = fmaf(p, w, 0.246640727f);
    p = fmaf(p, w, 1.50140941f);
  } else {
    w = sqrtf(w) - 3.0f;
    p = -0.000200214257f;
    p = fmaf(p, w, 0.000100950558f);
    p = fmaf(p, w, 0.00134934322f);
    p = fmaf(p, w, -0.00367342844f);
    p = fmaf(p, w, 0.00573950773f);
    p = fmaf(p, w, -0.0076224613f);
    p = fmaf(p, w, 0.00943887047f);
    p = fmaf(p, w, 1.00167406f);
    p = fmaf(p, w, 2.83297682f);
  }
  return p * x;
}

__device__ __forceinline__ float jax_normal(uint32_t k0, uint32_t k1, uint32_t e) {
  uint32_t x0 = 0u, x1 = e;
  tf_block(k0, k1, x0, x1);
  uint32_t bits = x0 ^ x1;
  float u = __uint_as_float((bits >> 9) | 0x3f800000u) - 1.0f;
  float v = __fadd_rn(__fmul_rn(u, 2.0f), -0x1.fffffep-1f);
  v = fmaxf(v, -0x1.fffffep-1f);
  return __fmul_rn((float)1.4142135623730951, erfinv_xla(v));
}

// accurate sin of an EXACT f32 argument: f64 Cody-Waite reduction (verified R9)
__device__ __forceinline__ float sin_acc(float xf) {
  double x = (double)xf;
  double kd = rint(x * 6.3661977236758138e-01);
  double r = fma(-kd, 1.5707963267948966e+00, x);
  r = fma(-kd, 6.1232339957367660e-17, r);
  float rf = (float)r;
  float y = rf * rf;
  float ps = fmaf(y, 2.7557319e-06f, -1.9841270e-04f);
  ps = fmaf(y, ps, 8.3333335e-03f);
  ps = fmaf(y, ps, -0.16666667f);
  float s = fmaf(rf * y, ps, rf);
  float pc = fmaf(y, -2.7557319e-07f, 2.4801587e-05f);
  pc = fmaf(y, pc, -1.3888889e-03f);
  pc = fmaf(y, pc, 4.1666668e-02f);
  pc = fmaf(y, pc, -0.5f);
  float c = fmaf(y, pc, 1.0f);
  int q = ((int)kd) & 3;
  float rs = (q & 1) ? c : s;
  return (q & 2) ? -rs : rs;
}

__device__ __forceinline__ float apply_act(float v, int act) {
  switch (act) {
    case ACT_LRELU:    return v >= 0.0f ? v : 0.1f * v;
    case ACT_SOFTPLUS: return fmaxf(v, 0.0f) + log1pf(expf(-fabsf(v)));
    case ACT_SIGMOID:  return 1.0f / (1.0f + expf(-v));
  }
  return v;
}

// ---------------- conv kernels ----------------
// Tiled K=3 conv: block = 64 t-lanes x 4 o-groups, thread computes 4 CONTIGUOUS
// outputs (o0+4*og+i). Weights staged in LDS (coalesced once per chunk), read
// back as aligned float4 broadcasts. FMA chain per output: cc ascending, k 0..2,
// acc seeded from bias -> bitwise identical to reference.
__global__ void __launch_bounds__(256) conv3_tiled(
    const float* __restrict__ x, const float* __restrict__ w,
    const float* __restrict__ bias, float* __restrict__ y,
    int Cin, int Cout, int act) {
  __shared__ float sx[K3C][66];
  __shared__ __align__(16) float sw[K3C][52];  // [cc][o_local*3+k], row padded to 52
  int t0 = blockIdx.x * 64;
  int o0 = blockIdx.y * 16;
  int b = blockIdx.z;
  int lane = threadIdx.x & 63;
  int og = threadIdx.x >> 6;
  int t = t0 + lane;
  int o[4];
  float acc[4];
#pragma unroll
  for (int i = 0; i < 4; ++i) {
    o[i] = o0 + 4 * og + i;
    acc[i] = (o[i] < Cout) ? bias[o[i]] : 0.0f;
  }
  for (int c0 = 0; c0 < Cin; c0 += K3C) {
    __syncthreads();
    for (int idx = threadIdx.x; idx < K3C * 66; idx += 256) {
      int cc = idx / 66, j = idx - cc * 66;
      int tt = t0 - 1 + j;
      sx[cc][j] = (tt >= 0 && tt < T_) ? x[((size_t)b * Cin + c0 + cc) * T_ + tt] : 0.0f;
    }
    // stage weights: 16 outputs x K3C cc x 3 k (coalesced 192-float runs per output)
    for (int idx = threadIdx.x; idx < 16 * K3C * 3; idx += 256) {
      int oo = idx / (K3C * 3), r = idx - oo * (K3C * 3);
      float v = (o0 + oo < Cout) ? w[((size_t)(o0 + oo) * Cin + c0) * 3 + r] : 0.0f;
      sw[r / 3][oo * 3 + (r % 3)] = v;
    }
    __syncthreads();
    for (int cc = 0; cc < K3C; ++cc) {
      float xm = sx[cc][lane];
      float x0v = sx[cc][lane + 1];
      float xp = sx[cc][lane + 2];
      const float4* wv4 = (const float4*)&sw[cc][og * 12];
      float4 wa = wv4[0], wb = wv4[1], wc = wv4[2];
      float wl[12] = {wa.x, wa.y, wa.z, wa.w, wb.x, wb.y, wb.z, wb.w,
                      wc.x, wc.y, wc.z, wc.w};
#pragma unroll
      for (int i = 0; i < 4; ++i) {
        acc[i] = fmaf(xm,  wl[3 * i + 0], acc[i]);
        acc[i] = fmaf(x0v, wl[3 * i + 1], acc[i]);
        acc[i] = fmaf(xp,  wl[3 * i + 2], acc[i]);
      }
    }
  }
  if (t < T_) {
#pragma unroll
    for (int i = 0; i < 4; ++i)
      if (o[i] < Cout) y[((size_t)b * Cout + o[i]) * T_ + t] = apply_act(acc[i], act);
  }
}

// Fused depthwise-K3 -> pointwise. dw result AND both weight sets staged in LDS.
// dw FMA chain identical to dw_conv3; pw accumulation ascends cc globally with
// acc seeded from bias -> bitwise identical to dw_conv3 followed by pw conv.
__global__ void __launch_bounds__(256) dwpw_tiled(
    const float* __restrict__ x, const float* __restrict__ wd,
    const float* __restrict__ bd, const float* __restrict__ wp,
    const float* __restrict__ bp, float* __restrict__ y,
    int Cin, int Cout, int act) {
  __shared__ float sx[DWC][66];
  __shared__ float sd[DWC][64];
  __shared__ __align__(16) float swp[DWC][20];  // [cc][o_local]
  __shared__ float swd[DWC][4];                 // [cc][{w0,w1,w2,bias}]
  int t0 = blockIdx.x * 64;
  int o0 = blockIdx.y * 16;
  int b = blockIdx.z;
  int lane = threadIdx.x & 63;
  int og = threadIdx.x >> 6;
  int t = t0 + lane;
  int o[4];
  float acc[4];
#pragma unroll
  for (int i = 0; i < 4; ++i) {
    o[i] = o0 + 4 * og + i;
    acc[i] = (o[i] < Cout) ? bp[o[i]] : 0.0f;
  }
  for (int c0 = 0; c0 < Cin; c0 += DWC) {
    __syncthreads();
    for (int idx = threadIdx.x; idx < DWC * 66; idx += 256) {
      int cc = idx / 66, j = idx - cc * 66;
      int tt = t0 - 1 + j;
      sx[cc][j] = (tt >= 0 && tt < T_) ? x[((size_t)b * Cin + c0 + cc) * T_ + tt] : 0.0f;
    }
    for (int idx = threadIdx.x; idx < DWC * 3; idx += 256) {
      int cc = idx / 3, k = idx - cc * 3;
      swd[cc][k] = wd[(size_t)(c0 + cc) * 3 + k];
    }
    if (threadIdx.x < DWC) swd[threadIdx.x][3] = bd[c0 + threadIdx.x];
    for (int idx = threadIdx.x; idx < 16 * DWC; idx += 256) {
      int oo = idx / DWC, cc = idx - oo * DWC;
      swp[cc][oo] = (o0 + oo < Cout) ? wp[(size_t)(o0 + oo) * Cin + c0 + cc] : 0.0f;
    }
    __syncthreads();
    // depthwise: output j corresponds to t = t0 + j
    for (int idx = threadIdx.x; idx < DWC * 64; idx += 256) {
      int cc = idx >> 6, j = idx & 63;
      sd[cc][j] = fmaf(sx[cc][j], swd[cc][0],
                  fmaf(sx[cc][j + 1], swd[cc][1],
                  fmaf(sx[cc][j + 2], swd[cc][2], swd[cc][3])));
    }
    __syncthreads();
    for (int cc = 0; cc < DWC; ++cc) {
      float xv = sd[cc][lane];
      float4 wv = *(const float4*)&swp[cc][4 * og];
      acc[0] = fmaf(xv, wv.x, acc[0]);
      acc[1] = fmaf(xv, wv.y, acc[1]);
      acc[2] = fmaf(xv, wv.z, acc[2]);
      acc[3] = fmaf(xv, wv.w, acc[3]);
    }
  }
  if (t < T_) {
#pragma unroll
    for (int i = 0; i < 4; ++i)
      if (o[i] < Cout) y[((size_t)b * Cout + o[i]) * T_ + t] = apply_act(acc[i], act);
  }
}

// Tiled K=1 pointwise conv, weights staged in LDS. cc ascending, acc=bias start
// -> bitwise identical.
__global__ void __launch_bounds__(256) pw_tiled(
    const float* __restrict__ x, const float* __restrict__ w,
    const float* __restrict__ bias, float* __restrict__ y,
    int Cin, int Cout, int act) {
  __shared__ float sx[PWC][64];
  __shared__ __align__(16) float sw[PWC][20];  // [cc][o_local]
  int t0 = blockIdx.x * 64;
  int o0 = blockIdx.y * 16;
  int b = blockIdx.z;
  int lane = threadIdx.x & 63;
  int og = threadIdx.x >> 6;
  int t = t0 + lane;
  int o[4];
  float acc[4];
#pragma unroll
  for (int i = 0; i < 4; ++i) {
    o[i] = o0 + 4 * og + i;
    acc[i] = (o[i] < Cout) ? bias[o[i]] : 0.0f;
  }
  for (int c0 = 0; c0 < Cin; c0 += PWC) {
    __syncthreads();
    for (int idx = threadIdx.x; idx < PWC * 64; idx += 256) {
      int cc = idx >> 6, j = idx & 63;
      int tt = t0 + j;
      sx[cc][j] = (tt < T_) ? x[((size_t)b * Cin + c0 + cc) * T_ + tt] : 0.0f;
    }
    for (int idx = threadIdx.x; idx < 16 * PWC; idx += 256) {
      int oo = idx / PWC, cc = idx - oo * PWC;
      sw[cc][oo] = (o0 + oo < Cout) ? w[(size_t)(o0 + oo) * Cin + c0 + cc] : 0.0f;
    }
    __syncthreads();
    for (int cc = 0; cc < PWC; ++cc) {
      float xv = sx[cc][lane];
      float4 wv = *(const float4*)&sw[cc][4 * og];
      acc[0] = fmaf(xv, wv.x, acc[0]);
      acc[1] = fmaf(xv, wv.y, acc[1]);
      acc[2] = fmaf(xv, wv.z, acc[2]);
      acc[3] = fmaf(xv, wv.w, acc[3]);
    }
  }
  if (t < T_) {
#pragma unroll
    for (int i = 0; i < 4; ++i)
      if (o[i] < Cout) y[((size_t)b * Cout + o[i]) * T_ + t] = apply_act(acc[i], act);
  }
}

__global__ void pw_small(const float* __restrict__ x, const float* __restrict__ w,
                         const float* __restrict__ bias, float* __restrict__ y,
                         int Cin, int Cout, int act) {
  int idx = blockIdx.x * blockDim.x + threadIdx.x;
  int total = B_ * Cout * T_;
  if (idx >= total) return;
  int t = idx % T_;
  int o = (idx / T_) % Cout;
  int b = idx / (T_ * Cout);
  float acc = bias[o];
  const float* wo = w + (size_t)o * Cin;
  const float* xb = x + (size_t)b * Cin * T_ + t;
  for (int cc = 0; cc < Cin; ++cc) acc = fmaf(wo[cc], xb[(size_t)cc * T_], acc);
  y[((size_t)b * Cout + o) * T_ + t] = apply_act(acc, act);
}

__global__ void shaped_kernel(const float* __restrict__ ha, const float* __restrict__ fp,
                              const float* __restrict__ f0, float* __restrict__ out) {
  int t = blockIdx.x, b = blockIdx.y, h = threadIdx.x;
  __shared__ float ff[5], nm[5];
  if (h < 10) {
    float v = fp[((size_t)b * 10 + h) * T_ + t];
    if (h < 5) {
      ff[h] = 200.0f + 3300.0f * (1.0f / (1.0f + expf(-v)));
    } else {
      float bw = 50.0f + 150.0f * (fmaxf(v, 0.0f) + log1pf(expf(-fabsf(v))));
      nm[h - 5] = bw * bw;
    }
  }
  __syncthreads();
  if (h >= NH_) return;
  float hfreq = (float)(h + 1) * f0[(size_t)b * T_ + t];
  float g = 1.0f;
  for (int i = 0; i < 5; ++i) {
    float d = hfreq - ff[i];
    float den = d * d + nm[i];
    float res = nm[i] / fmaxf(den, 1e-5f);
    g = g * (0.8f + 0.2f * res);
  }
  out[((size_t)b * NH_ + h) * T_ + t] = ha[((size_t)b * NH_ + h) * T_ + t] * g;
}

// ---- fused terms + RWR level-1: computes per-element term inline (identical
// f32 ops to the old terms_kernel), then the 16-wide inclusive prefix sum ----
__global__ void terms_l1(const float* __restrict__ f0, float* __restrict__ A1) {
  int gid = blockIdx.x * blockDim.x + threadIdx.x;
  if (gid >= B_ * N1_) return;
  int b = gid / N1_, w = gid - b * N1_;
  const float* f0b = f0 + (size_t)b * T_;
  float* a = A1 + (size_t)b * L_ + (size_t)w * 16;
  const float RINV = (float)(500.0 / 120000.0);
  float S = 0.0f;
  int lbase = w * 16;
  for (int i = 0; i < 16; ++i) {
    int l = lbase + i;
    float pos = __fsub_rn(__fmul_rn(__fadd_rn((float)l, 0.5f), RINV), 0.5f);
    pos = fminf(fmaxf(pos, 0.0f), 499.0f);
    int lo = (int)floorf(pos);
    int hi = lo + 1; hi = hi < (T_ - 1) ? hi : (T_ - 1);
    float wt = __fsub_rn(pos, (float)lo);
    float omw = __fsub_rn(1.0f, wt);
    float f0up = __fadd_rn(__fmul_rn(f0b[lo], omw), __fmul_rn(f0b[hi], wt));
    float trm = __fdiv_rn(__fmul_rn((float)6.283185307179586, f0up), 24000.0f);
    S = __fadd_rn(S, trm);
    a[i] = S;
  }
}

// ---- fused RWR mid-chain: l2,l3,l4,l5,e3,e2 in ONE single-block kernel.
// __syncthreads() between phases gives block-wide global-memory visibility.
// Per-item arithmetic identical to the old rwr_l2..rwr_e2 kernels. ----
__global__ void __launch_bounds__(256) rwr_mid(
    const float* __restrict__ A1, float* __restrict__ A2, float* __restrict__ A3,
    float* __restrict__ A4, float* __restrict__ E5, float* __restrict__ E3o,
    float* __restrict__ E2o) {
  int tid = threadIdx.x;
  // l2
  for (int gid = tid; gid < B_ * N2_; gid += 256) {
    int b = gid / N2_, w = gid - b * N2_;
    float S = 0.0f;
    for (int m = 0; m < 16; ++m) {
      int i = w * 16 + m;
      float v = (i < N1_) ? A1[(size_t)b * L_ + (size_t)i * 16 + 15] : 0.0f;
      S = __fadd_rn(S, v);
      A2[(size_t)b * N2P_ + i] = S;
    }
  }
  __syncthreads();
  // l3
  for (int gid = tid; gid < B_ * N3_; gid += 256) {
    int b = gid / N3_, w = gid - b * N3_;
    float S = 0.0f;
    for (int m = 0; m < 16; ++m) {
      int i = w * 16 + m;
      float v = (i < N2_) ? A2[(size_t)b * N2P_ + (size_t)i * 16 + 15] : 0.0f;
      S = __fadd_rn(S, v);
      A3[(size_t)b * N3P_ + i] = S;
    }
  }
  __syncthreads();
  // l4
  for (int gid = tid; gid < B_ * N4_; gid += 256) {
    int b = gid / N4_, w = gid - b * N4_;
    float S = 0.0f;
    for (int m = 0; m < 16; ++m) {
      int i = w * 16 + m;
      float v = (i < N3_) ? A3[(size_t)b * N3P_ + (size_t)i * 16 + 15] : 0.0f;
      S = __fadd_rn(S, v);
      A4[(size_t)b * N4P_ + i] = S;
    }
  }
  __syncthreads();
  // l5
  if (tid < B_) {
    E5[tid * N4_ + 0] = 0.0f;
    E5[tid * N4_ + 1] = A4[(size_t)tid * N4P_ + 15];
  }
  __syncthreads();
  // e3
  for (int gid = tid; gid < B_ * N3_; gid += 256) {
    int b = gid / N3_, k = gid - b * N3_;
    float v = 0.0f;
    if (k > 0) {
      int i = k - 1;
      v = __fadd_rn(E5[b * N4_ + (i >> 4)], A4[(size_t)b * N4P_ + i]);
    }
    E3o[b * N3_ + k] = v;
  }
  __syncthreads();
  // e2
  for (int gid = tid; gid < B_ * N2_; gid += 256) {
    int b = gid / N2_, j = gid - b * N2_;
    float v = 0.0f;
    if (j > 0) {
      int i = j - 1;
      v = __fadd_rn(E3o[b * N3_ + (i >> 4)], A3[(size_t)b * N3P_ + i]);
    }
    E2o[b * N2_ + j] = v;
  }
}

// ---------------- main synthesis kernel (numerics unchanged; rwr_e1 inlined:
// E1o[b][r] == (r>0 ? __fadd_rn(E2o[b][(r-1)>>4], A2[b][r-1]) : 0)) ----------
__global__ void __launch_bounds__(256) main_kernel(
    const float* __restrict__ A1, const float* __restrict__ A2,
    const float* __restrict__ E2o,
    const float* __restrict__ shaped, const float* __restrict__ q,
    const float* __restrict__ f0, float* __restrict__ out,
    uint32_t k10, uint32_t k11, uint32_t k20, uint32_t k21, uint32_t k30, uint32_t k31) {
  const float RINV = (float)(500.0 / 120000.0);
  int b = blockIdx.y;
  int l0 = blockIdx.x * 256;
  int l = l0 + threadIdx.x;
  __shared__ float ls[4][NH_];
  float p0 = __fsub_rn(__fmul_rn(__fadd_rn((float)l0, 0.5f), RINV), 0.5f);
  p0 = fminf(fmaxf(p0, 0.0f), 499.0f);
  int lo0 = (int)floorf(p0);
  for (int i = threadIdx.x; i < 4 * NH_; i += 256) {
    int j = i / NH_, h = i - j * NH_;
    int col = lo0 + j; col = col < (T_ - 1) ? col : (T_ - 1);
    ls[j][h] = shaped[((size_t)b * NH_ + h) * T_ + col];
  }
  __syncthreads();
  if (l >= L_) return;

  float pos = __fsub_rn(__fmul_rn(__fadd_rn((float)l, 0.5f), RINV), 0.5f);
  pos = fminf(fmaxf(pos, 0.0f), 499.0f);
  int lo = (int)floorf(pos);
  int hi = lo + 1; hi = hi < (T_ - 1) ? hi : (T_ - 1);
  float w = __fsub_rn(pos, (float)lo);
  float omw = __fsub_rn(1.0f, w);

  const float* f0b = f0 + (size_t)b * T_;
  float f0up = __fadd_rn(__fmul_rn(f0b[lo], omw), __fmul_rn(f0b[hi], w));
  const float* qb = q + (size_t)b * 3 * T_;
  float q0 = __fadd_rn(__fmul_rn(qb[lo], omw), __fmul_rn(qb[hi], w));
  float q1 = __fadd_rn(__fmul_rn(qb[T_ + lo], omw), __fmul_rn(qb[T_ + hi], w));
  float q2 = __fadd_rn(__fmul_rn(qb[2 * T_ + lo], omw), __fmul_rn(qb[2 * T_ + hi], w));
  float jit = __fmul_rn(q0, 0.05f);
  float shm = __fmul_rn(q1, 0.15f);
  float brt = __fmul_rn(q2, 0.3f);

  uint32_t e = (uint32_t)(b * L_ + l);
  float n1 = jax_normal(k10, k11, e);
  float n2 = jax_normal(k20, k21, e);
  float n3 = jax_normal(k30, k31, e);

  // inlined rwr_e1
  float e1v = 0.0f;
  int r = l >> 4;
  if (r > 0) {
    int i = r - 1;
    e1v = __fadd_rn(E2o[b * N2_ + (i >> 4)], A2[(size_t)b * N2P_ + i]);
  }
  float phf = __fadd_rn(e1v, A1[(size_t)b * L_ + l]);
  float jph = __fadd_rn(phf, __fmul_rn(jit, n1));

  int jlo = lo - lo0;
  int jhi = hi - lo0; jhi = jhi < 3 ? jhi : 3;

  float acc = 0.0f;
  for (int h = 1; h <= NH_; ++h) {
    float amp = __fadd_rn(__fmul_rn(ls[jlo][h - 1], omw), __fmul_rn(ls[jhi][h - 1], w));
    float hf = (float)h;
    float arg = __fmul_rn(jph, hf);
    float s = sin_acc(arg);
    float m = (__fmul_rn(hf, f0up) < 12000.0f) ? 1.0f : 0.0f;
    acc = __fadd_rn(acc, __fmul_rn(__fmul_rn(amp, s), m));
  }
  float env = __fadd_rn(1.0f, __fmul_rn(n2, shm));
  out[(size_t)b * L_ + l] = __fadd_rn(__fmul_rn(acc, env), __fmul_rn(n3, brt));
}

extern "C" void kernel_launch(void* const* d_in, const int* in_sizes, int n_in,
                              void* d_out, int out_size, void* d_ws, size_t ws_size,
                              hipStream_t stream) {
  const float* f0    = (const float*)d_in[0];
  const float* cond  = (const float*)d_in[1];
  const float* ha_w1 = (const float*)d_in[2];
  const float* ha_b1 = (const float*)d_in[3];
  const float* ha_w2 = (const float*)d_in[4];
  const float* ha_b2 = (const float*)d_in[5];
  const float* ha_w3 = (const float*)d_in[6];
  const float* ha_b3 = (const float*)d_in[7];
  const float* ha_w4 = (const float*)d_in[8];
  const float* ha_b4 = (const float*)d_in[9];
  const float* ha_w5 = (const float*)d_in[10];
  const float* ha_b5 = (const float*)d_in[11];
  const float* fm_w1 = (const float*)d_in[12];
  const float* fm_b1 = (const float*)d_in[13];
  const float* fm_w2 = (const float*)d_in[14];
  const float* fm_b2 = (const float*)d_in[15];
  const float* fm_w3 = (const float*)d_in[16];
  const float* fm_b3 = (const float*)d_in[17];
  const float* vq_w1 = (const float*)d_in[18];
  const float* vq_b1 = (const float*)d_in[19];
  const float* vq_w2 = (const float*)d_in[20];
  const float* vq_b2 = (const float*)d_in[21];
  const float* vq_w3 = (const float*)d_in[22];
  const float* vq_b3 = (const float*)d_in[23];
  float* out = (float*)d_out;

  // split(key(42), 3), foldlike/partitionable (verified)
  uint32_t kw[3][2];
  for (uint32_t j = 0; j < 3; ++j) {
    uint32_t x0 = 0u, x1 = j;
    tf_block(0u, 42u, x0, x1);
    kw[j][0] = x0; kw[j][1] = x1;
  }

  // workspace layout (floats)
  float* ws = (float*)d_ws;
  size_t off = 0;
  auto take = [&](size_t n) { float* p = ws + off; off += (n + 3) & ~(size_t)3; return p; };
  float* Abuf = take(512000);
  float* Bb   = take(512000);
  float* C    = take(512000);
  float* ha   = take((size_t)B_ * NH_ * T_);
  float* fp   = take((size_t)B_ * 10 * T_);
  float* qv   = take((size_t)B_ * 3 * T_);
  float* sh   = take((size_t)B_ * NH_ * T_);
  float* A1   = take((size_t)B_ * L_);
  float* A2   = take((size_t)B_ * N2P_);
  float* A3   = take((size_t)B_ * N3P_);
  float* A4   = take((size_t)B_ * N4P_);
  float* E5   = take((size_t)B_ * N4_);
  float* E3o  = take((size_t)B_ * N3_);
  float* E2o  = take((size_t)B_ * N2_);

  // phase chain: 2 launches
  terms_l1<<<(B_ * N1_ + 255) / 256, 256, 0, stream>>>(f0, A1);
  rwr_mid<<<1, 256, 0, stream>>>(A1, A2, A3, A4, E5, E3o, E2o);

  // harmonic_amplitude_net
  dwpw_tiled<<<dim3(8, 16, B_), 256, 0, stream>>>(cond, ha_w1, ha_b1, ha_w2, ha_b2, Bb, 128, 256, ACT_LRELU);
  dwpw_tiled<<<dim3(8, 16, B_), 256, 0, stream>>>(Bb, ha_w3, ha_b3, ha_w4, ha_b4, C, 256, 256, ACT_LRELU);
  pw_tiled<<<dim3(8, 7, B_), 256, 0, stream>>>(C, ha_w5, ha_b5, ha, 256, 100, ACT_SOFTPLUS);
  // formant net
  conv3_tiled<<<dim3(8, 16, B_), 256, 0, stream>>>(cond, fm_w1, fm_b1, Abuf, 128, 256, ACT_LRELU);
  conv3_tiled<<<dim3(8, 16, B_), 256, 0, stream>>>(Abuf, fm_w2, fm_b2, C, 256, 256, ACT_LRELU);
  pw_small<<<(B_ * 10 * T_ + 255) / 256, 256, 0, stream>>>(C, fm_w3, fm_b3, fp, 256, 10, ACT_NONE);
  // voice-quality net
  conv3_tiled<<<dim3(8, 8, B_), 256, 0, stream>>>(cond, vq_w1, vq_b1, Bb, 128, 128, ACT_LRELU);
  conv3_tiled<<<dim3(8, 4, B_), 256, 0, stream>>>(Bb, vq_w2, vq_b2, Abuf, 128, 64, ACT_LRELU);
  pw_small<<<(B_ * 3 * T_ + 255) / 256, 256, 0, stream>>>(Abuf, vq_w3, vq_b3, qv, 64, 3, ACT_SIGMOID);
  // shaped amplitudes
  shaped_kernel<<<dim3(T_, B_), 128, 0, stream>>>(ha, fp, f0, sh);
  // synthesis (rwr_e1 inlined)
  main_kernel<<<dim3((L_ + 255) / 256, B_), 256, 0, stream>>>(
      A1, A2, E2o, sh, qv, f0, out,
      kw[0][0], kw[0][1], kw[1][0], kw[1][1], kw[2][0], kw[2][1]);
  (void)in_sizes; (void)n_in; (void)out_size; (void)ws_size;
}

// Round 3
// 296.310 us; speedup vs baseline: 1.9427x; 1.7731x over previous
//
#include <hip/hip_runtime.h>
#include <stdint.h>

#define B_ 4
#define T_ 500
#define L_ 120000
#define NH_ 100
// RWR(16) level sizes (verified R9 — DO NOT TOUCH)
#define N1_ 7500
#define N2_ 469
#define N2P_ 7504
#define N3_ 30
#define N3P_ 480
#define N4_ 2
#define N4P_ 32

#define ACT_NONE 0
#define ACT_LRELU 1
#define ACT_SOFTPLUS 2
#define ACT_SIGMOID 3

// ---------------- Threefry2x32-20 (verified R9) ----------------
__host__ __device__ __forceinline__ uint32_t tf_rotl(uint32_t v, int d) {
  return (v << d) | (v >> (32 - d));
}
__host__ __device__ __forceinline__ void tf_block(uint32_t k0, uint32_t k1,
                                                  uint32_t& x0, uint32_t& x1) {
  uint32_t k2 = k0 ^ k1 ^ 0x1BD11BDAu;
  x0 += k0; x1 += k1;
#define TF_R(d) x0 += x1; x1 = tf_rotl(x1, (d)); x1 ^= x0;
  TF_R(13) TF_R(15) TF_R(26) TF_R(6)   x0 += k1; x1 += k2 + 1u;
  TF_R(17) TF_R(29) TF_R(16) TF_R(24)  x0 += k2; x1 += k0 + 2u;
  TF_R(13) TF_R(15) TF_R(26) TF_R(6)   x0 += k0; x1 += k1 + 3u;
  TF_R(17) TF_R(29) TF_R(16) TF_R(24)  x0 += k1; x1 += k2 + 4u;
  TF_R(13) TF_R(15) TF_R(26) TF_R(6)   x0 += k2; x1 += k0 + 5u;
#undef TF_R
}

__device__ __forceinline__ float erfinv_xla(float x) {
  float w = -log1pf(-(x * x));
  float p;
  if (w < 5.0f) {
    w = w - 2.5f;
    p = 2.81022636e-08f;
    p = fmaf(p, w, 3.43273939e-07f);
    p = fmaf(p, w, -3.5233877e-06f);
    p = fmaf(p, w, -4.39150654e-06f);
    p = fmaf(p, w, 0.00021858087f);
    p = fmaf(p, w, -0.00125372503f);
    p = fmaf(p, w, -0.00417768164f);
    p = fmaf(p, w, 0.246640727f);
    p = fmaf(p, w, 1.50140941f);
  } else {
    w = sqrtf(w) - 3.0f;
    p = -0.000200214257f;
    p = fmaf(p, w, 0.000100950558f);
    p = fmaf(p, w, 0.00134934322f);
    p = fmaf(p, w, -0.00367342844f);
    p = fmaf(p, w, 0.00573950773f);
    p = fmaf(p, w, -0.0076224613f);
    p = fmaf(p, w, 0.00943887047f);
    p = fmaf(p, w, 1.00167406f);
    p = fmaf(p, w, 2.83297682f);
  }
  return p * x;
}

__device__ __forceinline__ float jax_normal(uint32_t k0, uint32_t k1, uint32_t e) {
  uint32_t x0 = 0u, x1 = e;
  tf_block(k0, k1, x0, x1);
  uint32_t bits = x0 ^ x1;
  float u = __uint_as_float((bits >> 9) | 0x3f800000u) - 1.0f;
  float v = __fadd_rn(__fmul_rn(u, 2.0f), -0x1.fffffep-1f);
  v = fmaxf(v, -0x1.fffffep-1f);
  return __fmul_rn((float)1.4142135623730951, erfinv_xla(v));
}

// accurate sin of an EXACT f32 argument: f64 Cody-Waite reduction (verified R9)
__device__ __forceinline__ float sin_acc(float xf) {
  double x = (double)xf;
  double kd = rint(x * 6.3661977236758138e-01);
  double r = fma(-kd, 1.5707963267948966e+00, x);
  r = fma(-kd, 6.1232339957367660e-17, r);
  float rf = (float)r;
  float y = rf * rf;
  float ps = fmaf(y, 2.7557319e-06f, -1.9841270e-04f);
  ps = fmaf(y, ps, 8.3333335e-03f);
  ps = fmaf(y, ps, -0.16666667f);
  float s = fmaf(rf * y, ps, rf);
  float pc = fmaf(y, -2.7557319e-07f, 2.4801587e-05f);
  pc = fmaf(y, pc, -1.3888889e-03f);
  pc = fmaf(y, pc, 4.1666668e-02f);
  pc = fmaf(y, pc, -0.5f);
  float c = fmaf(y, pc, 1.0f);
  int q = ((int)kd) & 3;
  float rs = (q & 1) ? c : s;
  return (q & 2) ? -rs : rs;
}

__device__ __forceinline__ float apply_act(float v, int act) {
  switch (act) {
    case ACT_LRELU:    return v >= 0.0f ? v : 0.1f * v;
    case ACT_SOFTPLUS: return fmaxf(v, 0.0f) + log1pf(expf(-fabsf(v)));
    case ACT_SIGMOID:  return 1.0f / (1.0f + expf(-v));
  }
  return v;
}

// ---------------- conv path device functions ----------------
// All paths: block = 64 t-lanes x 4 o-groups; thread computes 4 CONTIGUOUS
// outputs o = o0+4*og+i. Per-chunk register prefetch double-buffers global
// loads under compute. FMA chain per output: cc ascending (across chunks),
// k 0..2, acc seeded from bias -> bitwise identical to reference.

// K=3 conv. LDS: sx[64][68] + sw[64][52] = 7680 floats.
__device__ __forceinline__ void conv3_path(
    const float* __restrict__ x, const float* __restrict__ w,
    const float* __restrict__ bias, float* __restrict__ y,
    int Cin, int Cout, int o0, int act, int b, int t0, float* smem) {
  float* sxf = smem;            // [64][68]
  float* swf = smem + 64 * 68;  // [64][52]
  int tid = threadIdx.x;
  int lane = tid & 63, og = tid >> 6;
  int t = t0 + lane;
  int o[4]; float acc[4];
#pragma unroll
  for (int i = 0; i < 4; ++i) {
    o[i] = o0 + 4 * og + i;
    acc[i] = (o[i] < Cout) ? bias[o[i]] : 0.0f;
  }
  float rx[17], rw[12];
  const int nch = Cin >> 6;
  auto ld = [&](int c) {
    int cb = c * 64;
#pragma unroll
    for (int k = 0; k < 17; ++k) {
      int idx = tid + 256 * k;
      int cc = idx / 68, j = idx - cc * 68;
      int tt = t0 - 1 + j;
      rx[k] = (j < 66 && tt >= 0 && tt < T_)
                  ? x[((size_t)b * Cin + cb + cc) * T_ + tt] : 0.0f;
    }
#pragma unroll
    for (int k = 0; k < 12; ++k) {
      int idx = tid + 256 * k;
      int oo = idx / 192, r = idx - oo * 192;
      rw[k] = (o0 + oo < Cout) ? w[((size_t)(o0 + oo) * Cin + cb) * 3 + r] : 0.0f;
    }
  };
  ld(0);
  for (int c = 0; c < nch; ++c) {
    __syncthreads();
#pragma unroll
    for (int k = 0; k < 17; ++k) sxf[tid + 256 * k] = rx[k];
#pragma unroll
    for (int k = 0; k < 12; ++k) {
      int idx = tid + 256 * k;
      int oo = idx / 192, r = idx - oo * 192;
      swf[(r / 3) * 52 + oo * 3 + (r % 3)] = rw[k];
    }
    __syncthreads();
    if (c + 1 < nch) ld(c + 1);
    for (int cc = 0; cc < 64; ++cc) {
      float xm  = sxf[cc * 68 + lane];
      float x0v = sxf[cc * 68 + lane + 1];
      float xp  = sxf[cc * 68 + lane + 2];
      const float4* wv4 = (const float4*)&swf[cc * 52 + og * 12];
      float4 wa = wv4[0], wb = wv4[1], wc = wv4[2];
      float wl[12] = {wa.x, wa.y, wa.z, wa.w, wb.x, wb.y, wb.z, wb.w,
                      wc.x, wc.y, wc.z, wc.w};
#pragma unroll
      for (int i = 0; i < 4; ++i) {
        acc[i] = fmaf(xm,  wl[3 * i + 0], acc[i]);
        acc[i] = fmaf(x0v, wl[3 * i + 1], acc[i]);
        acc[i] = fmaf(xp,  wl[3 * i + 2], acc[i]);
      }
    }
  }
  if (t < T_) {
#pragma unroll
    for (int i = 0; i < 4; ++i)
      if (o[i] < Cout) y[((size_t)b * Cout + o[i]) * T_ + t] = apply_act(acc[i], act);
  }
}

// Fused depthwise-K3 -> pointwise. dw result computed into regs then written
// into the sx region (reused as sd[64][64]) -> LDS total 5888 floats.
// dw chain: fmaf(xm,w0,fmaf(x0,w1,fmaf(xp,w2,bias))) identical to reference;
// pw: cc ascending, bias-seeded -> bitwise identical to dw conv followed by pw.
__device__ __forceinline__ void dwpw_path(
    const float* __restrict__ x, const float* __restrict__ wd,
    const float* __restrict__ bd, const float* __restrict__ wp,
    const float* __restrict__ bp, float* __restrict__ y,
    int Cin, int Cout, int o0, int act, int b, int t0, float* smem) {
  float* sxf  = smem;          // [64][68]; reused as sd[64][64] after dw
  float* swdf = smem + 4352;   // [64][4]  {w0,w1,w2,bias}
  float* swpf = smem + 4608;   // [64][20] [cc][o_local]
  int tid = threadIdx.x;
  int lane = tid & 63, og = tid >> 6;
  int t = t0 + lane;
  int o[4]; float acc[4];
#pragma unroll
  for (int i = 0; i < 4; ++i) {
    o[i] = o0 + 4 * og + i;
    acc[i] = (o[i] < Cout) ? bp[o[i]] : 0.0f;
  }
  float rx[17], rwp[4], rwd1;
  const int nch = Cin >> 6;
  auto ld = [&](int c) {
    int cb = c * 64;
#pragma unroll
    for (int k = 0; k < 17; ++k) {
      int idx = tid + 256 * k;
      int cc = idx / 68, j = idx - cc * 68;
      int tt = t0 - 1 + j;
      rx[k] = (j < 66 && tt >= 0 && tt < T_)
                  ? x[((size_t)b * Cin + cb + cc) * T_ + tt] : 0.0f;
    }
    {
      int cc = tid >> 2, q = tid & 3;
      rwd1 = (q < 3) ? wd[(size_t)(cb + cc) * 3 + q] : bd[cb + cc];
    }
#pragma unroll
    for (int k = 0; k < 4; ++k) {
      int idx = tid + 256 * k;
      int oo = idx >> 6, cc = idx & 63;
      rwp[k] = (o0 + oo < Cout) ? wp[(size_t)(o0 + oo) * Cin + cb + cc] : 0.0f;
    }
  };
  ld(0);
  for (int c = 0; c < nch; ++c) {
    __syncthreads();
#pragma unroll
    for (int k = 0; k < 17; ++k) sxf[tid + 256 * k] = rx[k];
    swdf[tid] = rwd1;
#pragma unroll
    for (int k = 0; k < 4; ++k) {
      int idx = tid + 256 * k;
      int oo = idx >> 6, cc = idx & 63;
      swpf[cc * 20 + oo] = rwp[k];
    }
    __syncthreads();
    if (c + 1 < nch) ld(c + 1);
    // depthwise into regs: thread (og,lane) computes sd[og+4k][lane]
    float rd[16];
#pragma unroll
    for (int k = 0; k < 16; ++k) {
      int cc = og + 4 * k;
      rd[k] = fmaf(sxf[cc * 68 + lane], swdf[cc * 4 + 0],
              fmaf(sxf[cc * 68 + lane + 1], swdf[cc * 4 + 1],
              fmaf(sxf[cc * 68 + lane + 2], swdf[cc * 4 + 2], swdf[cc * 4 + 3])));
    }
    __syncthreads();  // all sx reads done before overwrite
#pragma unroll
    for (int k = 0; k < 16; ++k) sxf[(og + 4 * k) * 64 + lane] = rd[k];
    __syncthreads();
    for (int cc = 0; cc < 64; ++cc) {
      float xv = sxf[cc * 64 + lane];
      float4 wv = *(const float4*)&swpf[cc * 20 + og * 4];
      acc[0] = fmaf(xv, wv.x, acc[0]);
      acc[1] = fmaf(xv, wv.y, acc[1]);
      acc[2] = fmaf(xv, wv.z, acc[2]);
      acc[3] = fmaf(xv, wv.w, acc[3]);
    }
  }
  if (t < T_) {
#pragma unroll
    for (int i = 0; i < 4; ++i)
      if (o[i] < Cout) y[((size_t)b * Cout + o[i]) * T_ + t] = apply_act(acc[i], act);
  }
}

// K=1 pointwise. LDS: sx[64][64] + sw[64][20] = 5376 floats.
__device__ __forceinline__ void pw_path(
    const float* __restrict__ x, const float* __restrict__ w,
    const float* __restrict__ bias, float* __restrict__ y,
    int Cin, int Cout, int o0, int act, int b, int t0, float* smem) {
  float* sxf = smem;          // [64][64]
  float* swf = smem + 4096;   // [64][20]
  int tid = threadIdx.x;
  int lane = tid & 63, og = tid >> 6;
  int t = t0 + lane;
  int o[4]; float acc[4];
#pragma unroll
  for (int i = 0; i < 4; ++i) {
    o[i] = o0 + 4 * og + i;
    acc[i] = (o[i] < Cout) ? bias[o[i]] : 0.0f;
  }
  float rx[16], rw[4];
  const int nch = Cin >> 6;
  auto ld = [&](int c) {
    int cb = c * 64;
#pragma unroll
    for (int k = 0; k < 16; ++k) {
      int idx = tid + 256 * k;
      int cc = idx >> 6, j = idx & 63;
      int tt = t0 + j;
      rx[k] = (tt < T_) ? x[((size_t)b * Cin + cb + cc) * T_ + tt] : 0.0f;
    }
#pragma unroll
    for (int k = 0; k < 4; ++k) {
      int idx = tid + 256 * k;
      int oo = idx >> 6, cc = idx & 63;
      rw[k] = (o0 + oo < Cout) ? w[(size_t)(o0 + oo) * Cin + cb + cc] : 0.0f;
    }
  };
  ld(0);
  for (int c = 0; c < nch; ++c) {
    __syncthreads();
#pragma unroll
    for (int k = 0; k < 16; ++k) sxf[tid + 256 * k] = rx[k];
#pragma unroll
    for (int k = 0; k < 4; ++k) {
      int idx = tid + 256 * k;
      int oo = idx >> 6, cc = idx & 63;
      swf[cc * 20 + oo] = rw[k];
    }
    __syncthreads();
    if (c + 1 < nch) ld(c + 1);
    for (int cc = 0; cc < 64; ++cc) {
      float xv = sxf[cc * 64 + lane];
      float4 wv = *(const float4*)&swf[cc * 20 + og * 4];
      acc[0] = fmaf(xv, wv.x, acc[0]);
      acc[1] = fmaf(xv, wv.y, acc[1]);
      acc[2] = fmaf(xv, wv.z, acc[2]);
      acc[3] = fmaf(xv, wv.w, acc[3]);
    }
  }
  if (t < T_) {
#pragma unroll
    for (int i = 0; i < 4; ++i)
      if (o[i] < Cout) y[((size_t)b * Cout + o[i]) * T_ + t] = apply_act(acc[i], act);
  }
}

// ---- fused RWR mid-chain body: l2,l3,l4,l5,e3,e2 in one block (verified) ----
__device__ void rwr_body(const float* __restrict__ A1, float* __restrict__ A2,
                         float* __restrict__ A3, float* __restrict__ A4,
                         float* __restrict__ E5, float* __restrict__ E3o,
                         float* __restrict__ E2o) {
  int tid = threadIdx.x;
  for (int gid = tid; gid < B_ * N2_; gid += 256) {
    int b = gid / N2_, w = gid - b * N2_;
    float S = 0.0f;
    for (int m = 0; m < 16; ++m) {
      int i = w * 16 + m;
      float v = (i < N1_) ? A1[(size_t)b * L_ + (size_t)i * 16 + 15] : 0.0f;
      S = __fadd_rn(S, v);
      A2[(size_t)b * N2P_ + i] = S;
    }
  }
  __syncthreads();
  for (int gid = tid; gid < B_ * N3_; gid += 256) {
    int b = gid / N3_, w = gid - b * N3_;
    float S = 0.0f;
    for (int m = 0; m < 16; ++m) {
      int i = w * 16 + m;
      float v = (i < N2_) ? A2[(size_t)b * N2P_ + (size_t)i * 16 + 15] : 0.0f;
      S = __fadd_rn(S, v);
      A3[(size_t)b * N3P_ + i] = S;
    }
  }
  __syncthreads();
  for (int gid = tid; gid < B_ * N4_; gid += 256) {
    int b = gid / N4_, w = gid - b * N4_;
    float S = 0.0f;
    for (int m = 0; m < 16; ++m) {
      int i = w * 16 + m;
      float v = (i < N3_) ? A3[(size_t)b * N3P_ + (size_t)i * 16 + 15] : 0.0f;
      S = __fadd_rn(S, v);
      A4[(size_t)b * N4P_ + i] = S;
    }
  }
  __syncthreads();
  if (tid < B_) {
    E5[tid * N4_ + 0] = 0.0f;
    E5[tid * N4_ + 1] = A4[(size_t)tid * N4P_ + 15];
  }
  __syncthreads();
  for (int gid = tid; gid < B_ * N3_; gid += 256) {
    int b = gid / N3_, k = gid - b * N3_;
    float v = 0.0f;
    if (k > 0) {
      int i = k - 1;
      v = __fadd_rn(E5[b * N4_ + (i >> 4)], A4[(size_t)b * N4P_ + i]);
    }
    E3o[b * N3_ + k] = v;
  }
  __syncthreads();
  for (int gid = tid; gid < B_ * N2_; gid += 256) {
    int b = gid / N2_, j = gid - b * N2_;
    float v = 0.0f;
    if (j > 0) {
      int i = j - 1;
      v = __fadd_rn(E3o[b * N3_ + (i >> 4)], A3[(size_t)b * N3P_ + i]);
    }
    E2o[b * N2_ + j] = v;
  }
}

// ---------------- merged layer kernels ----------------
// L1: fm1 conv3 (y 0..15) | vq1 conv3 (y 16..23) | ha1 dwpw (y 24..39)
//     | rwr mid-chain (y 40, one block)
__global__ void __launch_bounds__(256) conv_l1(
    const float* __restrict__ cond,
    const float* __restrict__ fw1, const float* __restrict__ fb1,
    const float* __restrict__ vw1, const float* __restrict__ vb1,
    const float* __restrict__ hw1, const float* __restrict__ hb1,
    const float* __restrict__ hw2, const float* __restrict__ hb2,
    float* __restrict__ fmA, float* __restrict__ vqB, float* __restrict__ haB,
    const float* __restrict__ A1, float* __restrict__ A2, float* __restrict__ A3,
    float* __restrict__ A4, float* __restrict__ E5, float* __restrict__ E3o,
    float* __restrict__ E2o) {
  __shared__ __align__(16) float smem[7680];
  int yy = blockIdx.y, b = blockIdx.z, t0 = blockIdx.x * 64;
  if (yy < 16) {
    conv3_path(cond, fw1, fb1, fmA, 128, 256, yy * 16, ACT_LRELU, b, t0, smem);
  } else if (yy < 24) {
    conv3_path(cond, vw1, vb1, vqB, 128, 128, (yy - 16) * 16, ACT_LRELU, b, t0, smem);
  } else if (yy < 40) {
    dwpw_path(cond, hw1, hb1, hw2, hb2, haB, 128, 256, (yy - 24) * 16, ACT_LRELU, b, t0, smem);
  } else {
    if (blockIdx.x != 0 || blockIdx.z != 0) return;
    rwr_body(A1, A2, A3, A4, E5, E3o, E2o);
  }
}

// L2: fm2 conv3 (y 0..15) | vq2 conv3 (y 16..19) | ha2 dwpw (y 20..35)
__global__ void __launch_bounds__(256) conv_l2(
    const float* __restrict__ fmA, const float* __restrict__ vqB,
    const float* __restrict__ haB,
    const float* __restrict__ fw2, const float* __restrict__ fb2,
    const float* __restrict__ vw2, const float* __restrict__ vb2,
    const float* __restrict__ hw3, const float* __restrict__ hb3,
    const float* __restrict__ hw4, const float* __restrict__ hb4,
    float* __restrict__ fmC, float* __restrict__ vqC, float* __restrict__ haC) {
  __shared__ __align__(16) float smem[7680];
  int yy = blockIdx.y, b = blockIdx.z, t0 = blockIdx.x * 64;
  if (yy < 16) {
    conv3_path(fmA, fw2, fb2, fmC, 256, 256, yy * 16, ACT_LRELU, b, t0, smem);
  } else if (yy < 20) {
    conv3_path(vqB, vw2, vb2, vqC, 128, 64, (yy - 16) * 16, ACT_LRELU, b, t0, smem);
  } else {
    dwpw_path(haB, hw3, hb3, hw4, hb4, haC, 256, 256, (yy - 20) * 16, ACT_LRELU, b, t0, smem);
  }
}

// L3: ha5 pw 256->100 softplus (y 0..6) | fm3 pw 256->10 (y 7) | vq3 pw 64->3 sigmoid (y 8)
__global__ void __launch_bounds__(256) conv_l3(
    const float* __restrict__ haC, const float* __restrict__ fmC,
    const float* __restrict__ vqC,
    const float* __restrict__ hw5, const float* __restrict__ hb5,
    const float* __restrict__ fw3, const float* __restrict__ fb3,
    const float* __restrict__ vw3, const float* __restrict__ vb3,
    float* __restrict__ ha, float* __restrict__ fp, float* __restrict__ qv) {
  __shared__ __align__(16) float smem[5376];
  int yy = blockIdx.y, b = blockIdx.z, t0 = blockIdx.x * 64;
  if (yy < 7) {
    pw_path(haC, hw5, hb5, ha, 256, 100, yy * 16, ACT_SOFTPLUS, b, t0, smem);
  } else if (yy == 7) {
    pw_path(fmC, fw3, fb3, fp, 256, 10, 0, ACT_NONE, b, t0, smem);
  } else {
    pw_path(vqC, vw3, vb3, qv, 64, 3, 0, ACT_SIGMOID, b, t0, smem);
  }
}

__global__ void shaped_kernel(const float* __restrict__ ha, const float* __restrict__ fp,
                              const float* __restrict__ f0, float* __restrict__ out) {
  int t = blockIdx.x, b = blockIdx.y, h = threadIdx.x;
  __shared__ float ff[5], nm[5];
  if (h < 10) {
    float v = fp[((size_t)b * 10 + h) * T_ + t];
    if (h < 5) {
      ff[h] = 200.0f + 3300.0f * (1.0f / (1.0f + expf(-v)));
    } else {
      float bw = 50.0f + 150.0f * (fmaxf(v, 0.0f) + log1pf(expf(-fabsf(v))));
      nm[h - 5] = bw * bw;
    }
  }
  __syncthreads();
  if (h >= NH_) return;
  float hfreq = (float)(h + 1) * f0[(size_t)b * T_ + t];
  float g = 1.0f;
  for (int i = 0; i < 5; ++i) {
    float d = hfreq - ff[i];
    float den = d * d + nm[i];
    float res = nm[i] / fmaxf(den, 1e-5f);
    g = g * (0.8f + 0.2f * res);
  }
  out[((size_t)b * NH_ + h) * T_ + t] = ha[((size_t)b * NH_ + h) * T_ + t] * g;
}

// ---- fused terms + RWR level-1 (verified) ----
__global__ void terms_l1(const float* __restrict__ f0, float* __restrict__ A1) {
  int gid = blockIdx.x * blockDim.x + threadIdx.x;
  if (gid >= B_ * N1_) return;
  int b = gid / N1_, w = gid - b * N1_;
  const float* f0b = f0 + (size_t)b * T_;
  float* a = A1 + (size_t)b * L_ + (size_t)w * 16;
  const float RINV = (float)(500.0 / 120000.0);
  float S = 0.0f;
  int lbase = w * 16;
  for (int i = 0; i < 16; ++i) {
    int l = lbase + i;
    float pos = __fsub_rn(__fmul_rn(__fadd_rn((float)l, 0.5f), RINV), 0.5f);
    pos = fminf(fmaxf(pos, 0.0f), 499.0f);
    int lo = (int)floorf(pos);
    int hi = lo + 1; hi = hi < (T_ - 1) ? hi : (T_ - 1);
    float wt = __fsub_rn(pos, (float)lo);
    float omw = __fsub_rn(1.0f, wt);
    float f0up = __fadd_rn(__fmul_rn(f0b[lo], omw), __fmul_rn(f0b[hi], wt));
    float trm = __fdiv_rn(__fmul_rn((float)6.283185307179586, f0up), 24000.0f);
    S = __fadd_rn(S, trm);
    a[i] = S;
  }
}

// ---------------- main synthesis kernel (numerics unchanged; rwr_e1 inlined) --
__global__ void __launch_bounds__(256) main_kernel(
    const float* __restrict__ A1, const float* __restrict__ A2,
    const float* __restrict__ E2o,
    const float* __restrict__ shaped, const float* __restrict__ q,
    const float* __restrict__ f0, float* __restrict__ out,
    uint32_t k10, uint32_t k11, uint32_t k20, uint32_t k21, uint32_t k30, uint32_t k31) {
  const float RINV = (float)(500.0 / 120000.0);
  int b = blockIdx.y;
  int l0 = blockIdx.x * 256;
  int l = l0 + threadIdx.x;
  __shared__ float ls[4][NH_];
  float p0 = __fsub_rn(__fmul_rn(__fadd_rn((float)l0, 0.5f), RINV), 0.5f);
  p0 = fminf(fmaxf(p0, 0.0f), 499.0f);
  int lo0 = (int)floorf(p0);
  for (int i = threadIdx.x; i < 4 * NH_; i += 256) {
    int j = i / NH_, h = i - j * NH_;
    int col = lo0 + j; col = col < (T_ - 1) ? col : (T_ - 1);
    ls[j][h] = shaped[((size_t)b * NH_ + h) * T_ + col];
  }
  __syncthreads();
  if (l >= L_) return;

  float pos = __fsub_rn(__fmul_rn(__fadd_rn((float)l, 0.5f), RINV), 0.5f);
  pos = fminf(fmaxf(pos, 0.0f), 499.0f);
  int lo = (int)floorf(pos);
  int hi = lo + 1; hi = hi < (T_ - 1) ? hi : (T_ - 1);
  float w = __fsub_rn(pos, (float)lo);
  float omw = __fsub_rn(1.0f, w);

  const float* f0b = f0 + (size_t)b * T_;
  float f0up = __fadd_rn(__fmul_rn(f0b[lo], omw), __fmul_rn(f0b[hi], w));
  const float* qb = q + (size_t)b * 3 * T_;
  float q0 = __fadd_rn(__fmul_rn(qb[lo], omw), __fmul_rn(qb[hi], w));
  float q1 = __fadd_rn(__fmul_rn(qb[T_ + lo], omw), __fmul_rn(qb[T_ + hi], w));
  float q2 = __fadd_rn(__fmul_rn(qb[2 * T_ + lo], omw), __fmul_rn(qb[2 * T_ + hi], w));
  float jit = __fmul_rn(q0, 0.05f);
  float shm = __fmul_rn(q1, 0.15f);
  float brt = __fmul_rn(q2, 0.3f);

  uint32_t e = (uint32_t)(b * L_ + l);
  float n1 = jax_normal(k10, k11, e);
  float n2 = jax_normal(k20, k21, e);
  float n3 = jax_normal(k30, k31, e);

  float e1v = 0.0f;
  int r = l >> 4;
  if (r > 0) {
    int i = r - 1;
    e1v = __fadd_rn(E2o[b * N2_ + (i >> 4)], A2[(size_t)b * N2P_ + i]);
  }
  float phf = __fadd_rn(e1v, A1[(size_t)b * L_ + l]);
  float jph = __fadd_rn(phf, __fmul_rn(jit, n1));

  int jlo = lo - lo0;
  int jhi = hi - lo0; jhi = jhi < 3 ? jhi : 3;

  float acc = 0.0f;
  for (int h = 1; h <= NH_; ++h) {
    float amp = __fadd_rn(__fmul_rn(ls[jlo][h - 1], omw), __fmul_rn(ls[jhi][h - 1], w));
    float hf = (float)h;
    float arg = __fmul_rn(jph, hf);
    float s = sin_acc(arg);
    float m = (__fmul_rn(hf, f0up) < 12000.0f) ? 1.0f : 0.0f;
    acc = __fadd_rn(acc, __fmul_rn(__fmul_rn(amp, s), m));
  }
  float env = __fadd_rn(1.0f, __fmul_rn(n2, shm));
  out[(size_t)b * L_ + l] = __fadd_rn(__fmul_rn(acc, env), __fmul_rn(n3, brt));
}

extern "C" void kernel_launch(void* const* d_in, const int* in_sizes, int n_in,
                              void* d_out, int out_size, void* d_ws, size_t ws_size,
                              hipStream_t stream) {
  const float* f0    = (const float*)d_in[0];
  const float* cond  = (const float*)d_in[1];
  const float* ha_w1 = (const float*)d_in[2];
  const float* ha_b1 = (const float*)d_in[3];
  const float* ha_w2 = (const float*)d_in[4];
  const float* ha_b2 = (const float*)d_in[5];
  const float* ha_w3 = (const float*)d_in[6];
  const float* ha_b3 = (const float*)d_in[7];
  const float* ha_w4 = (const float*)d_in[8];
  const float* ha_b4 = (const float*)d_in[9];
  const float* ha_w5 = (const float*)d_in[10];
  const float* ha_b5 = (const float*)d_in[11];
  const float* fm_w1 = (const float*)d_in[12];
  const float* fm_b1 = (const float*)d_in[13];
  const float* fm_w2 = (const float*)d_in[14];
  const float* fm_b2 = (const float*)d_in[15];
  const float* fm_w3 = (const float*)d_in[16];
  const float* fm_b3 = (const float*)d_in[17];
  const float* vq_w1 = (const float*)d_in[18];
  const float* vq_b1 = (const float*)d_in[19];
  const float* vq_w2 = (const float*)d_in[20];
  const float* vq_b2 = (const float*)d_in[21];
  const float* vq_w3 = (const float*)d_in[22];
  const float* vq_b3 = (const float*)d_in[23];
  float* out = (float*)d_out;

  // split(key(42), 3), foldlike/partitionable (verified)
  uint32_t kw[3][2];
  for (uint32_t j = 0; j < 3; ++j) {
    uint32_t x0 = 0u, x1 = j;
    tf_block(0u, 42u, x0, x1);
    kw[j][0] = x0; kw[j][1] = x1;
  }

  // workspace layout (floats)
  float* ws = (float*)d_ws;
  size_t off = 0;
  auto take = [&](size_t n) { float* p = ws + off; off += (n + 3) & ~(size_t)3; return p; };
  float* fmA = take(512000);
  float* haB = take(512000);
  float* fmC = take(512000);
  float* haC = take(512000);
  float* vqB = take(256000);
  float* vqC = take(128000);
  float* A1  = take((size_t)B_ * L_);
  float* A2  = take((size_t)B_ * N2P_);
  float* A3  = take((size_t)B_ * N3P_);
  float* A4  = take((size_t)B_ * N4P_);
  float* E5  = take((size_t)B_ * N4_);
  float* E3o = take((size_t)B_ * N3_);
  float* E2o = take((size_t)B_ * N2_);
  // aliases into dead conv buffers (liveness verified):
  float* ha = fmA;            // written L3; fmA dead after L2
  float* fp = vqB;            // written L3; vqB dead after L2
  float* qv = vqB + 20480;    // written L3
  float* sh = haB;            // written shaped; haB dead after L2

  // phase chain start (A1 must precede conv_l1's rwr block)
  terms_l1<<<(B_ * N1_ + 255) / 256, 256, 0, stream>>>(f0, A1);
  // merged conv layers
  conv_l1<<<dim3(8, 41, B_), 256, 0, stream>>>(
      cond, fm_w1, fm_b1, vq_w1, vq_b1, ha_w1, ha_b1, ha_w2, ha_b2,
      fmA, vqB, haB, A1, A2, A3, A4, E5, E3o, E2o);
  conv_l2<<<dim3(8, 36, B_), 256, 0, stream>>>(
      fmA, vqB, haB, fm_w2, fm_b2, vq_w2, vq_b2, ha_w3, ha_b3, ha_w4, ha_b4,
      fmC, vqC, haC);
  conv_l3<<<dim3(8, 9, B_), 256, 0, stream>>>(
      haC, fmC, vqC, ha_w5, ha_b5, fm_w3, fm_b3, vq_w3, vq_b3, ha, fp, qv);
  // shaped amplitudes
  shaped_kernel<<<dim3(T_, B_), 128, 0, stream>>>(ha, fp, f0, sh);
  // synthesis (rwr_e1 inlined)
  main_kernel<<<dim3((L_ + 255) / 256, B_), 256, 0, stream>>>(
      A1, A2, E2o, sh, qv, f0, out,
      kw[0][0], kw[0][1], kw[1][0], kw[1][1], kw[2][0], kw[2][1]);
  (void)in_sizes; (void)n_in; (void)out_size; (void)ws_size;
}

// Round 4
// 293.275 us; speedup vs baseline: 1.9628x; 1.0103x over previous
//
#include <hip/hip_runtime.h>
#include <stdint.h>

#define B_ 4
#define T_ 500
#define L_ 120000
#define NH_ 100
// RWR(16) level sizes (verified R9 — DO NOT TOUCH)
#define N1_ 7500
#define N2_ 469
#define N2P_ 7504
#define N3_ 30
#define N3P_ 480
#define N4_ 2
#define N4P_ 32

#define ACT_NONE 0
#define ACT_LRELU 1
#define ACT_SOFTPLUS 2
#define ACT_SIGMOID 3

#define SXW 268  // sx row stride (multiple of 4; 258 cols used)

// ---------------- Threefry2x32-20 (verified R9) ----------------
__host__ __device__ __forceinline__ uint32_t tf_rotl(uint32_t v, int d) {
  return (v << d) | (v >> (32 - d));
}
__host__ __device__ __forceinline__ void tf_block(uint32_t k0, uint32_t k1,
                                                  uint32_t& x0, uint32_t& x1) {
  uint32_t k2 = k0 ^ k1 ^ 0x1BD11BDAu;
  x0 += k0; x1 += k1;
#define TF_R(d) x0 += x1; x1 = tf_rotl(x1, (d)); x1 ^= x0;
  TF_R(13) TF_R(15) TF_R(26) TF_R(6)   x0 += k1; x1 += k2 + 1u;
  TF_R(17) TF_R(29) TF_R(16) TF_R(24)  x0 += k2; x1 += k0 + 2u;
  TF_R(13) TF_R(15) TF_R(26) TF_R(6)   x0 += k0; x1 += k1 + 3u;
  TF_R(17) TF_R(29) TF_R(16) TF_R(24)  x0 += k1; x1 += k2 + 4u;
  TF_R(13) TF_R(15) TF_R(26) TF_R(6)   x0 += k2; x1 += k0 + 5u;
#undef TF_R
}

__device__ __forceinline__ float erfinv_xla(float x) {
  float w = -log1pf(-(x * x));
  float p;
  if (w < 5.0f) {
    w = w - 2.5f;
    p = 2.81022636e-08f;
    p = fmaf(p, w, 3.43273939e-07f);
    p = fmaf(p, w, -3.5233877e-06f);
    p = fmaf(p, w, -4.39150654e-06f);
    p = fmaf(p, w, 0.00021858087f);
    p = fmaf(p, w, -0.00125372503f);
    p = fmaf(p, w, -0.00417768164f);
    p = fmaf(p, w, 0.246640727f);
    p = fmaf(p, w, 1.50140941f);
  } else {
    w = sqrtf(w) - 3.0f;
    p = -0.000200214257f;
    p = fmaf(p, w, 0.000100950558f);
    p = fmaf(p, w, 0.00134934322f);
    p = fmaf(p, w, -0.00367342844f);
    p = fmaf(p, w, 0.00573950773f);
    p = fmaf(p, w, -0.0076224613f);
    p = fmaf(p, w, 0.00943887047f);
    p = fmaf(p, w, 1.00167406f);
    p = fmaf(p, w, 2.83297682f);
  }
  return p * x;
}

__device__ __forceinline__ float jax_normal(uint32_t k0, uint32_t k1, uint32_t e) {
  uint32_t x0 = 0u, x1 = e;
  tf_block(k0, k1, x0, x1);
  uint32_t bits = x0 ^ x1;
  float u = __uint_as_float((bits >> 9) | 0x3f800000u) - 1.0f;
  float v = __fadd_rn(__fmul_rn(u, 2.0f), -0x1.fffffep-1f);
  v = fmaxf(v, -0x1.fffffep-1f);
  return __fmul_rn((float)1.4142135623730951, erfinv_xla(v));
}

// accurate sin of an EXACT f32 argument: f64 Cody-Waite reduction (verified R9)
__device__ __forceinline__ float sin_acc(float xf) {
  double x = (double)xf;
  double kd = rint(x * 6.3661977236758138e-01);
  double r = fma(-kd, 1.5707963267948966e+00, x);
  r = fma(-kd, 6.1232339957367660e-17, r);
  float rf = (float)r;
  float y = rf * rf;
  float ps = fmaf(y, 2.7557319e-06f, -1.9841270e-04f);
  ps = fmaf(y, ps, 8.3333335e-03f);
  ps = fmaf(y, ps, -0.16666667f);
  float s = fmaf(rf * y, ps, rf);
  float pc = fmaf(y, -2.7557319e-07f, 2.4801587e-05f);
  pc = fmaf(y, pc, -1.3888889e-03f);
  pc = fmaf(y, pc, 4.1666668e-02f);
  pc = fmaf(y, pc, -0.5f);
  float c = fmaf(y, pc, 1.0f);
  int q = ((int)kd) & 3;
  float rs = (q & 1) ? c : s;
  return (q & 2) ? -rs : rs;
}

__device__ __forceinline__ float apply_act(float v, int act) {
  switch (act) {
    case ACT_LRELU:    return v >= 0.0f ? v : 0.1f * v;
    case ACT_SOFTPLUS: return fmaxf(v, 0.0f) + log1pf(expf(-fabsf(v)));
    case ACT_SIGMOID:  return 1.0f / (1.0f + expf(-v));
  }
  return v;
}

// ---------------- conv path device functions ----------------
// Geometry: block 256 thr = 4 waves. wave: og = w&1 (8-output group), th = w>>1
// (t-half). Thread computes 8 outputs x 2 adjacent t. Block tile: 16 outputs x
// 256 t. Chunk = 32 channels. Register prefetch double-buffers global->LDS.
// FMA chain per output: cc ascending across chunks, k 0..2, acc seeded from
// bias -> bitwise identical to reference.

// K=3 conv. LDS: sx[32][268] (258 used) + sw[32][52] = 10240 floats.
__device__ __forceinline__ void conv3_path(
    const float* __restrict__ x, const float* __restrict__ w,
    const float* __restrict__ bias, float* __restrict__ y,
    int Cin, int Cout, int o0, int act, int b, int t0, float* smem) {
  float* sxf = smem;              // [32][SXW], row j: x[t0-1+j], j<258
  float* swf = smem + 32 * SXW;   // [32][52]: [cc][o_local*3+k]
  int tid = threadIdx.x;
  int lane = tid & 63;
  int wid = tid >> 6;
  int og = wid & 1, th = wid >> 1;
  int tl = th * 128 + 2 * lane;
  int t = t0 + tl;
  int obase = o0 + og * 8;
  float acc[8][2];
#pragma unroll
  for (int i = 0; i < 8; ++i) {
    float bv = (obase + i < Cout) ? bias[obase + i] : 0.0f;
    acc[i][0] = bv; acc[i][1] = bv;
  }
  float rx[33], rw[6];
  const int nch = Cin >> 5;
  auto ld = [&](int c) {
    int cb = c * 32;
#pragma unroll
    for (int k = 0; k < 33; ++k) {
      int idx = tid + 256 * k;
      int cc = idx / 258, j = idx - cc * 258;
      int tt = t0 - 1 + j;
      rx[k] = (idx < 8256 && tt >= 0 && tt < T_)
                  ? x[((size_t)b * Cin + cb + cc) * T_ + tt] : 0.0f;
    }
#pragma unroll
    for (int k = 0; k < 6; ++k) {
      int idx = tid + 256 * k;
      int oo = idx / 96, r = idx - oo * 96;
      rw[k] = (o0 + oo < Cout) ? w[((size_t)(o0 + oo) * Cin + cb) * 3 + r] : 0.0f;
    }
  };
  ld(0);
  for (int c = 0; c < nch; ++c) {
    __syncthreads();
#pragma unroll
    for (int k = 0; k < 33; ++k) {
      int idx = tid + 256 * k;
      if (idx < 8256) {
        int cc = idx / 258, j = idx - cc * 258;
        sxf[cc * SXW + j] = rx[k];
      }
    }
#pragma unroll
    for (int k = 0; k < 6; ++k) {
      int idx = tid + 256 * k;
      int oo = idx / 96, r = idx - oo * 96;
      swf[(r / 3) * 52 + oo * 3 + (r % 3)] = rw[k];
    }
    __syncthreads();
    if (c + 1 < nch) ld(c + 1);
    for (int cc = 0; cc < 32; ++cc) {
      const float* row = sxf + cc * SXW + tl;
      float2 xa = *(const float2*)row;        // x[t-1], x[t]
      float2 xb = *(const float2*)(row + 2);  // x[t+1], x[t+2]
      const float4* wq = (const float4*)(swf + cc * 52 + og * 24);
      float4 wA = wq[0], wB = wq[1], wC = wq[2], wD = wq[3], wE = wq[4], wF = wq[5];
      float wl[24] = {wA.x, wA.y, wA.z, wA.w, wB.x, wB.y, wB.z, wB.w,
                      wC.x, wC.y, wC.z, wC.w, wD.x, wD.y, wD.z, wD.w,
                      wE.x, wE.y, wE.z, wE.w, wF.x, wF.y, wF.z, wF.w};
#pragma unroll
      for (int i = 0; i < 8; ++i) {
        float w0 = wl[3 * i], w1 = wl[3 * i + 1], w2 = wl[3 * i + 2];
        acc[i][0] = fmaf(xa.x, w0, acc[i][0]);
        acc[i][0] = fmaf(xa.y, w1, acc[i][0]);
        acc[i][0] = fmaf(xb.x, w2, acc[i][0]);
        acc[i][1] = fmaf(xa.y, w0, acc[i][1]);
        acc[i][1] = fmaf(xb.x, w1, acc[i][1]);
        acc[i][1] = fmaf(xb.y, w2, acc[i][1]);
      }
    }
  }
#pragma unroll
  for (int i = 0; i < 8; ++i) {
    int o = obase + i;
    if (o < Cout) {
      if (t < T_)     y[((size_t)b * Cout + o) * T_ + t]     = apply_act(acc[i][0], act);
      if (t + 1 < T_) y[((size_t)b * Cout + o) * T_ + t + 1] = apply_act(acc[i][1], act);
    }
  }
}

// Fused depthwise-K3 -> pointwise. dw into regs (float4 rolling window), then
// written back into the sx region (reused as sd[cc][t_local]).
// dw chain fmaf(xm,w0,fmaf(x0,w1,fmaf(xp,w2,bias))) identical to reference;
// pw cc ascending, bias-seeded -> bitwise identical to dw conv followed by pw.
__device__ __forceinline__ void dwpw_path(
    const float* __restrict__ x, const float* __restrict__ wd,
    const float* __restrict__ bd, const float* __restrict__ wp,
    const float* __restrict__ bp, float* __restrict__ y,
    int Cin, int Cout, int o0, int act, int b, int t0, float* smem) {
  float* sxf  = smem;               // [32][SXW]; reused as sd after dw
  float* swdf = smem + 32 * SXW;    // [32][4]  {w0,w1,w2,bias}
  float* swpf = swdf + 128;         // [32][20] [cc][o_local]
  int tid = threadIdx.x;
  int lane = tid & 63;
  int wid = tid >> 6;
  int og = wid & 1, th = wid >> 1;
  int tl = th * 128 + 2 * lane;
  int t = t0 + tl;
  int obase = o0 + og * 8;
  float acc[8][2];
#pragma unroll
  for (int i = 0; i < 8; ++i) {
    float bv = (obase + i < Cout) ? bp[obase + i] : 0.0f;
    acc[i][0] = bv; acc[i][1] = bv;
  }
  float rx[33], rwp[2], rwd1 = 0.0f;
  const int nch = Cin >> 5;
  auto ld = [&](int c) {
    int cb = c * 32;
#pragma unroll
    for (int k = 0; k < 33; ++k) {
      int idx = tid + 256 * k;
      int cc = idx / 258, j = idx - cc * 258;
      int tt = t0 - 1 + j;
      rx[k] = (idx < 8256 && tt >= 0 && tt < T_)
                  ? x[((size_t)b * Cin + cb + cc) * T_ + tt] : 0.0f;
    }
    if (tid < 128) {
      int cc = tid >> 2, q = tid & 3;
      rwd1 = (q < 3) ? wd[(size_t)(cb + cc) * 3 + q] : bd[cb + cc];
    }
#pragma unroll
    for (int k = 0; k < 2; ++k) {
      int idx = tid + 256 * k;
      int oo = idx >> 5, cc = idx & 31;
      rwp[k] = (o0 + oo < Cout) ? wp[(size_t)(o0 + oo) * Cin + cb + cc] : 0.0f;
    }
  };
  ld(0);
  for (int c = 0; c < nch; ++c) {
    __syncthreads();
#pragma unroll
    for (int k = 0; k < 33; ++k) {
      int idx = tid + 256 * k;
      if (idx < 8256) {
        int cc = idx / 258, j = idx - cc * 258;
        sxf[cc * SXW + j] = rx[k];
      }
    }
    if (tid < 128) swdf[tid] = rwd1;
#pragma unroll
    for (int k = 0; k < 2; ++k) {
      int idx = tid + 256 * k;
      int oo = idx >> 5, cc = idx & 31;
      swpf[cc * 20 + oo] = rwp[k];
    }
    __syncthreads();
    // depthwise: thread (ccd, tseg) computes sd[ccd][tseg*32 .. +31]
    {
      int ccd = tid & 31, tseg = tid >> 5;
      const float* row = sxf + ccd * SXW + tseg * 32;  // row[i] = x[t-1+i]
      float dw0 = swdf[ccd * 4 + 0], dw1 = swdf[ccd * 4 + 1];
      float dw2 = swdf[ccd * 4 + 2], dw3 = swdf[ccd * 4 + 3];
      float rd[32];
      float4 va = *(const float4*)row;
#pragma unroll
      for (int m = 0; m < 8; ++m) {
        float4 vb = *(const float4*)(row + 4 * m + 4);
        rd[4 * m + 0] = fmaf(va.x, dw0, fmaf(va.y, dw1, fmaf(va.z, dw2, dw3)));
        rd[4 * m + 1] = fmaf(va.y, dw0, fmaf(va.z, dw1, fmaf(va.w, dw2, dw3)));
        rd[4 * m + 2] = fmaf(va.z, dw0, fmaf(va.w, dw1, fmaf(vb.x, dw2, dw3)));
        rd[4 * m + 3] = fmaf(va.w, dw0, fmaf(vb.x, dw1, fmaf(vb.y, dw2, dw3)));
        va = vb;
      }
      __syncthreads();  // all x reads done before overwrite
      float* drow = sxf + ccd * SXW + tseg * 32;
#pragma unroll
      for (int m = 0; m < 8; ++m)
        *(float4*)(drow + 4 * m) =
            make_float4(rd[4 * m], rd[4 * m + 1], rd[4 * m + 2], rd[4 * m + 3]);
    }
    __syncthreads();
    if (c + 1 < nch) ld(c + 1);
    for (int cc = 0; cc < 32; ++cc) {
      float2 xv = *(const float2*)(sxf + cc * SXW + tl);
      const float4* wq = (const float4*)(swpf + cc * 20 + og * 8);
      float4 wA = wq[0], wB = wq[1];
      float wl[8] = {wA.x, wA.y, wA.z, wA.w, wB.x, wB.y, wB.z, wB.w};
#pragma unroll
      for (int i = 0; i < 8; ++i) {
        acc[i][0] = fmaf(xv.x, wl[i], acc[i][0]);
        acc[i][1] = fmaf(xv.y, wl[i], acc[i][1]);
      }
    }
  }
#pragma unroll
  for (int i = 0; i < 8; ++i) {
    int o = obase + i;
    if (o < Cout) {
      if (t < T_)     y[((size_t)b * Cout + o) * T_ + t]     = apply_act(acc[i][0], act);
      if (t + 1 < T_) y[((size_t)b * Cout + o) * T_ + t + 1] = apply_act(acc[i][1], act);
    }
  }
}

// K=1 pointwise. Block tile: 32 outputs (4 og x 8) x 128 t (Nt=2).
// LDS: sx[32][128] + sw[32][36] = 5248 floats.
__device__ __forceinline__ void pw_path(
    const float* __restrict__ x, const float* __restrict__ w,
    const float* __restrict__ bias, float* __restrict__ y,
    int Cin, int Cout, int o0, int act, int b, int t0, float* smem) {
  float* sxf = smem;              // [32][128]
  float* swf = smem + 32 * 128;   // [32][36]
  int tid = threadIdx.x;
  int lane = tid & 63;
  int og = tid >> 6;
  int tl = 2 * lane;
  int t = t0 + tl;
  int obase = o0 + og * 8;
  float acc[8][2];
#pragma unroll
  for (int i = 0; i < 8; ++i) {
    float bv = (obase + i < Cout) ? bias[obase + i] : 0.0f;
    acc[i][0] = bv; acc[i][1] = bv;
  }
  float rx[16], rw[4];
  const int nch = Cin >> 5;
  auto ld = [&](int c) {
    int cb = c * 32;
#pragma unroll
    for (int k = 0; k < 16; ++k) {
      int idx = tid + 256 * k;
      int cc = idx >> 7, j = idx & 127;
      int tt = t0 + j;
      rx[k] = (tt < T_) ? x[((size_t)b * Cin + cb + cc) * T_ + tt] : 0.0f;
    }
#pragma unroll
    for (int k = 0; k < 4; ++k) {
      int idx = tid + 256 * k;
      int oo = idx >> 5, cc = idx & 31;
      rw[k] = (o0 + oo < Cout) ? w[(size_t)(o0 + oo) * Cin + cb + cc] : 0.0f;
    }
  };
  ld(0);
  for (int c = 0; c < nch; ++c) {
    __syncthreads();
#pragma unroll
    for (int k = 0; k < 16; ++k) {
      int idx = tid + 256 * k;
      int cc = idx >> 7, j = idx & 127;
      sxf[cc * 128 + j] = rx[k];
    }
#pragma unroll
    for (int k = 0; k < 4; ++k) {
      int idx = tid + 256 * k;
      int oo = idx >> 5, cc = idx & 31;
      swf[cc * 36 + oo] = rw[k];
    }
    __syncthreads();
    if (c + 1 < nch) ld(c + 1);
    for (int cc = 0; cc < 32; ++cc) {
      float2 xv = *(const float2*)(sxf + cc * 128 + tl);
      const float4* wq = (const float4*)(swf + cc * 36 + og * 8);
      float4 wA = wq[0], wB = wq[1];
      float wl[8] = {wA.x, wA.y, wA.z, wA.w, wB.x, wB.y, wB.z, wB.w};
#pragma unroll
      for (int i = 0; i < 8; ++i) {
        acc[i][0] = fmaf(xv.x, wl[i], acc[i][0]);
        acc[i][1] = fmaf(xv.y, wl[i], acc[i][1]);
      }
    }
  }
#pragma unroll
  for (int i = 0; i < 8; ++i) {
    int o = obase + i;
    if (o < Cout) {
      if (t < T_)     y[((size_t)b * Cout + o) * T_ + t]     = apply_act(acc[i][0], act);
      if (t + 1 < T_) y[((size_t)b * Cout + o) * T_ + t + 1] = apply_act(acc[i][1], act);
    }
  }
}

// ---- fused RWR mid-chain body: l2,l3,l4,l5,e3,e2 in one block (verified) ----
__device__ void rwr_body(const float* __restrict__ A1, float* __restrict__ A2,
                         float* __restrict__ A3, float* __restrict__ A4,
                         float* __restrict__ E5, float* __restrict__ E3o,
                         float* __restrict__ E2o) {
  int tid = threadIdx.x;
  for (int gid = tid; gid < B_ * N2_; gid += 256) {
    int b = gid / N2_, w = gid - b * N2_;
    float S = 0.0f;
    for (int m = 0; m < 16; ++m) {
      int i = w * 16 + m;
      float v = (i < N1_) ? A1[(size_t)b * L_ + (size_t)i * 16 + 15] : 0.0f;
      S = __fadd_rn(S, v);
      A2[(size_t)b * N2P_ + i] = S;
    }
  }
  __syncthreads();
  for (int gid = tid; gid < B_ * N3_; gid += 256) {
    int b = gid / N3_, w = gid - b * N3_;
    float S = 0.0f;
    for (int m = 0; m < 16; ++m) {
      int i = w * 16 + m;
      float v = (i < N2_) ? A2[(size_t)b * N2P_ + (size_t)i * 16 + 15] : 0.0f;
      S = __fadd_rn(S, v);
      A3[(size_t)b * N3P_ + i] = S;
    }
  }
  __syncthreads();
  for (int gid = tid; gid < B_ * N4_; gid += 256) {
    int b = gid / N4_, w = gid - b * N4_;
    float S = 0.0f;
    for (int m = 0; m < 16; ++m) {
      int i = w * 16 + m;
      float v = (i < N3_) ? A3[(size_t)b * N3P_ + (size_t)i * 16 + 15] : 0.0f;
      S = __fadd_rn(S, v);
      A4[(size_t)b * N4P_ + i] = S;
    }
  }
  __syncthreads();
  if (tid < B_) {
    E5[tid * N4_ + 0] = 0.0f;
    E5[tid * N4_ + 1] = A4[(size_t)tid * N4P_ + 15];
  }
  __syncthreads();
  for (int gid = tid; gid < B_ * N3_; gid += 256) {
    int b = gid / N3_, k = gid - b * N3_;
    float v = 0.0f;
    if (k > 0) {
      int i = k - 1;
      v = __fadd_rn(E5[b * N4_ + (i >> 4)], A4[(size_t)b * N4P_ + i]);
    }
    E3o[b * N3_ + k] = v;
  }
  __syncthreads();
  for (int gid = tid; gid < B_ * N2_; gid += 256) {
    int b = gid / N2_, j = gid - b * N2_;
    float v = 0.0f;
    if (j > 0) {
      int i = j - 1;
      v = __fadd_rn(E3o[b * N3_ + (i >> 4)], A3[(size_t)b * N3P_ + i]);
    }
    E2o[b * N2_ + j] = v;
  }
}

// ---------------- merged layer kernels ----------------
// L1: fm1 conv3 (y 0..15) | vq1 conv3 (y 16..23) | ha1 dwpw (y 24..39)
__global__ void __launch_bounds__(256) conv_l1(
    const float* __restrict__ cond,
    const float* __restrict__ fw1, const float* __restrict__ fb1,
    const float* __restrict__ vw1, const float* __restrict__ vb1,
    const float* __restrict__ hw1, const float* __restrict__ hb1,
    const float* __restrict__ hw2, const float* __restrict__ hb2,
    float* __restrict__ fmA, float* __restrict__ vqB, float* __restrict__ haB) {
  __shared__ __align__(16) float smem[32 * SXW + 32 * 52];
  int yy = blockIdx.y, b = blockIdx.z, t0 = blockIdx.x * 256;
  if (yy < 16) {
    conv3_path(cond, fw1, fb1, fmA, 128, 256, yy * 16, ACT_LRELU, b, t0, smem);
  } else if (yy < 24) {
    conv3_path(cond, vw1, vb1, vqB, 128, 128, (yy - 16) * 16, ACT_LRELU, b, t0, smem);
  } else {
    dwpw_path(cond, hw1, hb1, hw2, hb2, haB, 128, 256, (yy - 24) * 16, ACT_LRELU, b, t0, smem);
  }
}

// L2: fm2 conv3 (y 0..15) | vq2 conv3 (y 16..19) | ha2 dwpw (y 20..35)
//     | rwr mid-chain (y 36, one block)
__global__ void __launch_bounds__(256) conv_l2(
    const float* __restrict__ fmA, const float* __restrict__ vqB,
    const float* __restrict__ haB,
    const float* __restrict__ fw2, const float* __restrict__ fb2,
    const float* __restrict__ vw2, const float* __restrict__ vb2,
    const float* __restrict__ hw3, const float* __restrict__ hb3,
    const float* __restrict__ hw4, const float* __restrict__ hb4,
    float* __restrict__ fmC, float* __restrict__ vqC, float* __restrict__ haC,
    const float* __restrict__ A1, float* __restrict__ A2, float* __restrict__ A3,
    float* __restrict__ A4, float* __restrict__ E5, float* __restrict__ E3o,
    float* __restrict__ E2o) {
  __shared__ __align__(16) float smem[32 * SXW + 32 * 52];
  int yy = blockIdx.y, b = blockIdx.z, t0 = blockIdx.x * 256;
  if (yy < 16) {
    conv3_path(fmA, fw2, fb2, fmC, 256, 256, yy * 16, ACT_LRELU, b, t0, smem);
  } else if (yy < 20) {
    conv3_path(vqB, vw2, vb2, vqC, 128, 64, (yy - 16) * 16, ACT_LRELU, b, t0, smem);
  } else if (yy < 36) {
    dwpw_path(haB, hw3, hb3, hw4, hb4, haC, 256, 256, (yy - 20) * 16, ACT_LRELU, b, t0, smem);
  } else {
    if (blockIdx.x != 0 || blockIdx.z != 0) return;
    rwr_body(A1, A2, A3, A4, E5, E3o, E2o);
  }
}

// L3: ha5 pw 256->100 softplus (y 0..3) | fm3 pw 256->10 (y 4) | vq3 pw 64->3 (y 5)
__global__ void __launch_bounds__(256) conv_l3(
    const float* __restrict__ haC, const float* __restrict__ fmC,
    const float* __restrict__ vqC,
    const float* __restrict__ hw5, const float* __restrict__ hb5,
    const float* __restrict__ fw3, const float* __restrict__ fb3,
    const float* __restrict__ vw3, const float* __restrict__ vb3,
    float* __restrict__ ha, float* __restrict__ fp, float* __restrict__ qv) {
  __shared__ __align__(16) float smem[32 * 128 + 32 * 36];
  int yy = blockIdx.y, b = blockIdx.z, t0 = blockIdx.x * 128;
  if (yy < 4) {
    pw_path(haC, hw5, hb5, ha, 256, 100, yy * 32, ACT_SOFTPLUS, b, t0, smem);
  } else if (yy == 4) {
    pw_path(fmC, fw3, fb3, fp, 256, 10, 0, ACT_NONE, b, t0, smem);
  } else {
    pw_path(vqC, vw3, vb3, qv, 64, 3, 0, ACT_SIGMOID, b, t0, smem);
  }
}

__global__ void shaped_kernel(const float* __restrict__ ha, const float* __restrict__ fp,
                              const float* __restrict__ f0, float* __restrict__ out) {
  int t = blockIdx.x, b = blockIdx.y, h = threadIdx.x;
  __shared__ float ff[5], nm[5];
  if (h < 10) {
    float v = fp[((size_t)b * 10 + h) * T_ + t];
    if (h < 5) {
      ff[h] = 200.0f + 3300.0f * (1.0f / (1.0f + expf(-v)));
    } else {
      float bw = 50.0f + 150.0f * (fmaxf(v, 0.0f) + log1pf(expf(-fabsf(v))));
      nm[h - 5] = bw * bw;
    }
  }
  __syncthreads();
  if (h >= NH_) return;
  float hfreq = (float)(h + 1) * f0[(size_t)b * T_ + t];
  float g = 1.0f;
  for (int i = 0; i < 5; ++i) {
    float d = hfreq - ff[i];
    float den = d * d + nm[i];
    float res = nm[i] / fmaxf(den, 1e-5f);
    g = g * (0.8f + 0.2f * res);
  }
  out[((size_t)b * NH_ + h) * T_ + t] = ha[((size_t)b * NH_ + h) * T_ + t] * g;
}

// ---- fused terms + RWR level-1 (verified) ----
__global__ void terms_l1(const float* __restrict__ f0, float* __restrict__ A1) {
  int gid = blockIdx.x * blockDim.x + threadIdx.x;
  if (gid >= B_ * N1_) return;
  int b = gid / N1_, w = gid - b * N1_;
  const float* f0b = f0 + (size_t)b * T_;
  float* a = A1 + (size_t)b * L_ + (size_t)w * 16;
  const float RINV = (float)(500.0 / 120000.0);
  float S = 0.0f;
  int lbase = w * 16;
  for (int i = 0; i < 16; ++i) {
    int l = lbase + i;
    float pos = __fsub_rn(__fmul_rn(__fadd_rn((float)l, 0.5f), RINV), 0.5f);
    pos = fminf(fmaxf(pos, 0.0f), 499.0f);
    int lo = (int)floorf(pos);
    int hi = lo + 1; hi = hi < (T_ - 1) ? hi : (T_ - 1);
    float wt = __fsub_rn(pos, (float)lo);
    float omw = __fsub_rn(1.0f, wt);
    float f0up = __fadd_rn(__fmul_rn(f0b[lo], omw), __fmul_rn(f0b[hi], wt));
    float trm = __fdiv_rn(__fmul_rn((float)6.283185307179586, f0up), 24000.0f);
    S = __fadd_rn(S, trm);
    a[i] = S;
  }
}

// ---------------- main synthesis kernel (numerics unchanged; rwr_e1 inlined) --
__global__ void __launch_bounds__(256) main_kernel(
    const float* __restrict__ A1, const float* __restrict__ A2,
    const float* __restrict__ E2o,
    const float* __restrict__ shaped, const float* __restrict__ q,
    const float* __restrict__ f0, float* __restrict__ out,
    uint32_t k10, uint32_t k11, uint32_t k20, uint32_t k21, uint32_t k30, uint32_t k31) {
  const float RINV = (float)(500.0 / 120000.0);
  int b = blockIdx.y;
  int l0 = blockIdx.x * 256;
  int l = l0 + threadIdx.x;
  __shared__ float ls[4][NH_];
  float p0 = __fsub_rn(__fmul_rn(__fadd_rn((float)l0, 0.5f), RINV), 0.5f);
  p0 = fminf(fmaxf(p0, 0.0f), 499.0f);
  int lo0 = (int)floorf(p0);
  for (int i = threadIdx.x; i < 4 * NH_; i += 256) {
    int j = i / NH_, h = i - j * NH_;
    int col = lo0 + j; col = col < (T_ - 1) ? col : (T_ - 1);
    ls[j][h] = shaped[((size_t)b * NH_ + h) * T_ + col];
  }
  __syncthreads();
  if (l >= L_) return;

  float pos = __fsub_rn(__fmul_rn(__fadd_rn((float)l, 0.5f), RINV), 0.5f);
  pos = fminf(fmaxf(pos, 0.0f), 499.0f);
  int lo = (int)floorf(pos);
  int hi = lo + 1; hi = hi < (T_ - 1) ? hi : (T_ - 1);
  float w = __fsub_rn(pos, (float)lo);
  float omw = __fsub_rn(1.0f, w);

  const float* f0b = f0 + (size_t)b * T_;
  float f0up = __fadd_rn(__fmul_rn(f0b[lo], omw), __fmul_rn(f0b[hi], w));
  const float* qb = q + (size_t)b * 3 * T_;
  float q0 = __fadd_rn(__fmul_rn(qb[lo], omw), __fmul_rn(qb[hi], w));
  float q1 = __fadd_rn(__fmul_rn(qb[T_ + lo], omw), __fmul_rn(qb[T_ + hi], w));
  float q2 = __fadd_rn(__fmul_rn(qb[2 * T_ + lo], omw), __fmul_rn(qb[2 * T_ + hi], w));
  float jit = __fmul_rn(q0, 0.05f);
  float shm = __fmul_rn(q1, 0.15f);
  float brt = __fmul_rn(q2, 0.3f);

  uint32_t e = (uint32_t)(b * L_ + l);
  float n1 = jax_normal(k10, k11, e);
  float n2 = jax_normal(k20, k21, e);
  float n3 = jax_normal(k30, k31, e);

  float e1v = 0.0f;
  int r = l >> 4;
  if (r > 0) {
    int i = r - 1;
    e1v = __fadd_rn(E2o[b * N2_ + (i >> 4)], A2[(size_t)b * N2P_ + i]);
  }
  float phf = __fadd_rn(e1v, A1[(size_t)b * L_ + l]);
  float jph = __fadd_rn(phf, __fmul_rn(jit, n1));

  int jlo = lo - lo0;
  int jhi = hi - lo0; jhi = jhi < 3 ? jhi : 3;

  float acc = 0.0f;
  for (int h = 1; h <= NH_; ++h) {
    float amp = __fadd_rn(__fmul_rn(ls[jlo][h - 1], omw), __fmul_rn(ls[jhi][h - 1], w));
    float hf = (float)h;
    float arg = __fmul_rn(jph, hf);
    float s = sin_acc(arg);
    float m = (__fmul_rn(hf, f0up) < 12000.0f) ? 1.0f : 0.0f;
    acc = __fadd_rn(acc, __fmul_rn(__fmul_rn(amp, s), m));
  }
  float env = __fadd_rn(1.0f, __fmul_rn(n2, shm));
  out[(size_t)b * L_ + l] = __fadd_rn(__fmul_rn(acc, env), __fmul_rn(n3, brt));
}

extern "C" void kernel_launch(void* const* d_in, const int* in_sizes, int n_in,
                              void* d_out, int out_size, void* d_ws, size_t ws_size,
                              hipStream_t stream) {
  const float* f0    = (const float*)d_in[0];
  const float* cond  = (const float*)d_in[1];
  const float* ha_w1 = (const float*)d_in[2];
  const float* ha_b1 = (const float*)d_in[3];
  const float* ha_w2 = (const float*)d_in[4];
  const float* ha_b2 = (const float*)d_in[5];
  const float* ha_w3 = (const float*)d_in[6];
  const float* ha_b3 = (const float*)d_in[7];
  const float* ha_w4 = (const float*)d_in[8];
  const float* ha_b4 = (const float*)d_in[9];
  const float* ha_w5 = (const float*)d_in[10];
  const float* ha_b5 = (const float*)d_in[11];
  const float* fm_w1 = (const float*)d_in[12];
  const float* fm_b1 = (const float*)d_in[13];
  const float* fm_w2 = (const float*)d_in[14];
  const float* fm_b2 = (const float*)d_in[15];
  const float* fm_w3 = (const float*)d_in[16];
  const float* fm_b3 = (const float*)d_in[17];
  const float* vq_w1 = (const float*)d_in[18];
  const float* vq_b1 = (const float*)d_in[19];
  const float* vq_w2 = (const float*)d_in[20];
  const float* vq_b2 = (const float*)d_in[21];
  const float* vq_w3 = (const float*)d_in[22];
  const float* vq_b3 = (const float*)d_in[23];
  float* out = (float*)d_out;

  // split(key(42), 3), foldlike/partitionable (verified)
  uint32_t kw[3][2];
  for (uint32_t j = 0; j < 3; ++j) {
    uint32_t x0 = 0u, x1 = j;
    tf_block(0u, 42u, x0, x1);
    kw[j][0] = x0; kw[j][1] = x1;
  }

  // workspace layout (floats)
  float* ws = (float*)d_ws;
  size_t off = 0;
  auto take = [&](size_t n) { float* p = ws + off; off += (n + 3) & ~(size_t)3; return p; };
  float* fmA = take(512000);
  float* haB = take(512000);
  float* fmC = take(512000);
  float* haC = take(512000);
  float* vqB = take(256000);
  float* vqC = take(128000);
  float* A1  = take((size_t)B_ * L_);
  float* A2  = take((size_t)B_ * N2P_);
  float* A3  = take((size_t)B_ * N3P_);
  float* A4  = take((size_t)B_ * N4P_);
  float* E5  = take((size_t)B_ * N4_);
  float* E3o = take((size_t)B_ * N3_);
  float* E2o = take((size_t)B_ * N2_);
  // aliases into dead conv buffers (liveness verified):
  float* ha = fmA;            // written L3; fmA dead after L2
  float* fp = vqB;            // written L3; vqB dead after L2
  float* qv = vqB + 20480;    // written L3
  float* sh = haB;            // written shaped; haB dead after L2

  // phase chain start (A1 must precede conv_l2's rwr block)
  terms_l1<<<(B_ * N1_ + 255) / 256, 256, 0, stream>>>(f0, A1);
  // merged conv layers
  conv_l1<<<dim3(2, 40, B_), 256, 0, stream>>>(
      cond, fm_w1, fm_b1, vq_w1, vq_b1, ha_w1, ha_b1, ha_w2, ha_b2,
      fmA, vqB, haB);
  conv_l2<<<dim3(2, 37, B_), 256, 0, stream>>>(
      fmA, vqB, haB, fm_w2, fm_b2, vq_w2, vq_b2, ha_w3, ha_b3, ha_w4, ha_b4,
      fmC, vqC, haC, A1, A2, A3, A4, E5, E3o, E2o);
  conv_l3<<<dim3(4, 6, B_), 256, 0, stream>>>(
      haC, fmC, vqC, ha_w5, ha_b5, fm_w3, fm_b3, vq_w3, vq_b3, ha, fp, qv);
  // shaped amplitudes
  shaped_kernel<<<dim3(T_, B_), 128, 0, stream>>>(ha, fp, f0, sh);
  // synthesis (rwr_e1 inlined)
  main_kernel<<<dim3((L_ + 255) / 256, B_), 256, 0, stream>>>(
      A1, A2, E2o, sh, qv, f0, out,
      kw[0][0], kw[0][1], kw[1][0], kw[1][1], kw[2][0], kw[2][1]);
  (void)in_sizes; (void)n_in; (void)out_size; (void)ws_size;
}